// Round 3
// baseline (359.841 us; speedup 1.0000x reference)
//
#include <hip/hip_runtime.h>
#include <math.h>

#define BDIM 256
constexpr int BB = 4, Cc = 128, Hh = 128, Wd = 128, HW = Hh * Wd;
constexpr float EPSv = 1e-5f;

typedef __attribute__((ext_vector_type(8))) short short8v;
typedef __attribute__((ext_vector_type(4))) float floatx4;

#define MFMA16(a, b, c) __builtin_amdgcn_mfma_f32_16x16x32_bf16((a), (b), (c), 0, 0, 0)

__device__ __forceinline__ float sigmoidf_(float v) { return 1.f / (1.f + __expf(-v)); }

__device__ __forceinline__ unsigned short f2bf(float f) {
    union { float f; unsigned u; } v; v.f = f;
    unsigned r = v.u + 0x7FFFu + ((v.u >> 16) & 1u);
    return (unsigned short)(r >> 16);
}

// ---- weight repack into per-lane MFMA fragment order ----
// dst[cot][chunk][tap][lane][i] = w[co=cot*16+(lane&15)][ci=chunk*32+(lane>>4)*8+i][tap]
__global__ void repack_conv_k(const float* __restrict__ w, unsigned short* __restrict__ dst,
                              int ncot, int cout) {
    int idx = blockIdx.x * BDIM + threadIdx.x;
    int total = ncot * 4 * 9 * 64 * 8;
    if (idx >= total) return;
    int i = idx & 7;
    int lane = (idx >> 3) & 63;
    int tap = (idx >> 9) % 9;
    int chunk = (idx / (9 * 512)) & 3;
    int cot = idx / (4 * 9 * 512);
    int co = cot * 16 + (lane & 15);
    int ci = chunk * 32 + (lane >> 4) * 8 + i;
    float v = (co < cout) ? w[((size_t)co * Cc + ci) * 9 + tap] : 0.f;
    dst[idx] = f2bf(v);
}

// off(18)+mask(9) merged, padded to 32 couts (2 cotiles)
__global__ void repack_om_k(const float* __restrict__ w_off, const float* __restrict__ w_mask,
                            unsigned short* __restrict__ dst) {
    int idx = blockIdx.x * BDIM + threadIdx.x;
    int total = 2 * 4 * 9 * 64 * 8;
    if (idx >= total) return;
    int i = idx & 7;
    int lane = (idx >> 3) & 63;
    int tap = (idx >> 9) % 9;
    int chunk = (idx / (9 * 512)) & 3;
    int cot = idx / (4 * 9 * 512);
    int co = cot * 16 + (lane & 15);
    int ci = chunk * 32 + (lane >> 4) * 8 + i;
    float v = 0.f;
    if (co < 18)      v = w_off[((size_t)co * Cc + ci) * 9 + tap];
    else if (co < 27) v = w_mask[((size_t)(co - 18) * Cc + ci) * 9 + tap];
    dst[idx] = f2bf(v);
}

__global__ void pack_bom_k(const float* __restrict__ b_off, const float* __restrict__ b_mask,
                           float* __restrict__ bom) {
    int i = threadIdx.x;
    if (i < 32) bom[i] = (i < 18) ? b_off[i] : (i < 27 ? b_mask[i - 18] : 0.f);
}

// ---- MFMA implicit-GEMM conv3x3 (pad=1). Block: COTPB*16 couts x 128 px (one row). ----
template <int COTPB, int WCO>
__global__ __launch_bounds__(256) void convmf_k(
    const float* __restrict__ x, const unsigned short* __restrict__ wpk,
    const float* __restrict__ biasA, const float* __restrict__ biasB,
    int bsplit, int sigsplit,
    float* __restrict__ out, int ldc, int ch0) {
    constexpr int WPX = 4 / WCO;
    constexpr int PS = 8 / WPX;  // px-subtiles per wave
    const int cb = blockIdx.x, h = blockIdx.y, b = blockIdx.z;
    const int t = threadIdx.x;
    const int lane = t & 63, llo = t & 15, lhi = (t >> 4) & 3;
    const int wid = t >> 6;
    const int wr = wid / WPX, wc = wid % WPX;

    __shared__ unsigned short xs[3][4][132][8];

    floatx4 acc[2][PS];
#pragma unroll
    for (int c = 0; c < 2; c++)
#pragma unroll
        for (int ps = 0; ps < PS; ps++) acc[c][ps] = (floatx4){0.f, 0.f, 0.f, 0.f};

    const float* xb = x + (size_t)b * Cc * HW;

    for (int chunk = 0; chunk < 4; ++chunk) {
        __syncthreads();
        for (int task = t; task < 3120; task += BDIM) {
            int j = task % 130;
            int rc = task / 130;
            int r = rc >> 3, ci4 = rc & 7;
            int hh = h + r - 1, col = j - 1;
            float v0 = 0.f, v1 = 0.f, v2 = 0.f, v3 = 0.f;
            if ((unsigned)hh < (unsigned)Hh && (unsigned)col < (unsigned)Wd) {
                const float* p = xb + (size_t)(chunk * 32 + ci4 * 4) * HW + hh * Wd + col;
                v0 = p[0]; v1 = p[HW]; v2 = p[2 * HW]; v3 = p[3 * HW];
            }
            ushort4 u;
            u.x = f2bf(v0); u.y = f2bf(v1); u.z = f2bf(v2); u.w = f2bf(v3);
            *(ushort4*)&xs[r][ci4 >> 1][j][(ci4 & 1) * 4] = u;
        }
        __syncthreads();
#pragma unroll
        for (int tap = 0; tap < 9; ++tap) {
            const int r = tap / 3, dx = tap % 3;
            short8v af[2];
#pragma unroll
            for (int c = 0; c < 2; c++) {
                int cot = cb * COTPB + wr * 2 + c;
                af[c] = *(const short8v*)(wpk + ((((size_t)cot * 4 + chunk) * 9 + tap) * 64 + lane) * 8);
            }
            short8v bf[PS];
#pragma unroll
            for (int ps = 0; ps < PS; ps++)
                bf[ps] = *(const short8v*)&xs[r][lhi][wc * (PS * 16) + ps * 16 + llo + dx][0];
#pragma unroll
            for (int c = 0; c < 2; c++)
#pragma unroll
                for (int ps = 0; ps < PS; ps++)
                    acc[c][ps] = MFMA16(af[c], bf[ps], acc[c][ps]);
        }
    }

    const int cbase = cb * (COTPB * 16);
    const float* bp = (cbase < bsplit) ? biasA : biasB;
    const int bshift = (cbase < bsplit) ? 0 : bsplit;
    const bool dosig = cbase < sigsplit;
#pragma unroll
    for (int c = 0; c < 2; c++)
#pragma unroll
        for (int ps = 0; ps < PS; ps++)
#pragma unroll
            for (int reg = 0; reg < 4; reg++) {
                int co = cbase + (wr * 2 + c) * 16 + lhi * 4 + reg;
                int px = wc * (PS * 16) + ps * 16 + llo;
                float v = acc[c][ps][reg] + bp[co - bshift];
                if (dosig) v = sigmoidf_(v);
                out[((size_t)b * ldc + ch0 + co) * HW + h * Wd + px] = v;
            }
}

// ---- instance-norm stats ----
__global__ __launch_bounds__(256) void inorm_stats_k(const float* __restrict__ src,
                                                     float* __restrict__ mu, float* __restrict__ rsig,
                                                     int chTot, int ch0) {
    const int bc = blockIdx.x;
    const int b = bc >> 7, c = bc & 127;
    const float4* p = (const float4*)(src + ((size_t)b * chTot + ch0 + c) * HW);
    float s = 0.f, s2 = 0.f;
    for (int i = threadIdx.x; i < HW / 4; i += BDIM) {
        float4 v = p[i];
        s += v.x + v.y + v.z + v.w;
        s2 += v.x * v.x + v.y * v.y + v.z * v.z + v.w * v.w;
    }
    __shared__ float ss[BDIM], sq[BDIM];
    int t = threadIdx.x;
    ss[t] = s; sq[t] = s2;
    __syncthreads();
    for (int off = BDIM / 2; off > 0; off >>= 1) {
        if (t < off) { ss[t] += ss[t + off]; sq[t] += sq[t + off]; }
        __syncthreads();
    }
    if (t == 0) {
        float m = ss[0] / HW;
        float var = sq[0] / HW - m * m;
        mu[bc] = m;
        rsig[bc] = rsqrtf(var + EPSv);
    }
}

// ---- xa = lrelu(norm(featRaw)) * attn ----
__global__ void xattned_k(const float* __restrict__ rawAF, const float* __restrict__ mu,
                          const float* __restrict__ rsig, float* __restrict__ xa) {
    size_t i4 = (size_t)blockIdx.x * BDIM + threadIdx.x;
    const size_t n4 = (size_t)BB * Cc * HW / 4;
    if (i4 >= n4) return;
    int plane = (int)(i4 / (HW / 4));
    int w4 = (int)(i4 % (HW / 4));
    int b = plane >> 7, c = plane & 127;
    const float4 a = *(const float4*)(rawAF + ((size_t)b * 256 + c) * HW + w4 * 4);
    float4 f = *(const float4*)(rawAF + ((size_t)b * 256 + 128 + c) * HW + w4 * 4);
    float m = mu[plane], rs = rsig[plane];
    float4 o;
    float v;
    v = (f.x - m) * rs; v = v > 0.f ? v : 0.2f * v; o.x = v * a.x;
    v = (f.y - m) * rs; v = v > 0.f ? v : 0.2f * v; o.y = v * a.y;
    v = (f.z - m) * rs; v = v > 0.f ? v : 0.2f * v; o.z = v * a.z;
    v = (f.w - m) * rs; v = v > 0.f ? v : 0.2f * v; o.w = v * a.w;
    *(float4*)(xa + (size_t)plane * HW + w4 * 4) = o;
}

// ---- deformable conv: batched-load gather -> bf16 im2col LDS -> MFMA ----
__global__ __launch_bounds__(256, 4) void deform_mfma_k(
    const float* __restrict__ xa, const float* __restrict__ om,
    const unsigned short* __restrict__ wpkO, const float* __restrict__ b_org,
    float* __restrict__ out, int ldc, int ch0) {
    const int seg = blockIdx.x, h = blockIdx.y, b = blockIdx.z;
    const int t = threadIdx.x;
    const int lane = t & 63, llo = t & 15, lhi = (t >> 4) & 3;
    const int wid = t >> 6;

    __shared__ unsigned short sv[4][9][64][8];  // [cigrp][tap][px][ci8]

    // per-thread gather tables. units 0..575 = tap*64+px.
    // unit u=0: t; u=1: t+256; u=2: 512 + t/4 (only t%4==0) -> spread across waves.
    int prA[3][4];
    float prW[3][4];
    int prOff[3];
    bool prV[3];

    const float* omb = om + (size_t)b * 32 * HW;
#pragma unroll
    for (int u = 0; u < 3; u++) {
        bool valid;
        int pc;
        if (u < 2) { valid = true; pc = t + u * 256; }
        else { valid = (t & 3) == 0; pc = 512 + (t >> 2); }
        int tap = pc >> 6, pxl = pc & 63;
        int ww = seg * 64 + pxl;
        int pix = h * Wd + ww;
        float dy = omb[(size_t)(2 * tap) * HW + pix];
        float dxv = omb[(size_t)(2 * tap + 1) * HW + pix];
        float msk = sigmoidf_(omb[(size_t)(18 + tap) * HW + pix]);
        float yy = dy + (float)(h + tap / 3 - 1);
        float xx = dxv + (float)(ww + tap % 3 - 1);
        float y0f = floorf(yy), x0f = floorf(xx);
        float wy = yy - y0f, wx = xx - x0f;
        int y0 = (int)y0f, x0 = (int)x0f;
#pragma unroll
        for (int c2 = 0; c2 < 4; c2++) {
            int ddy = c2 >> 1, ddx = c2 & 1;
            int yi = y0 + ddy, xi = x0 + ddx;
            bool vc = (yi >= 0) && (yi < Hh) && (xi >= 0) && (xi < Wd);
            int yc = min(max(yi, 0), Hh - 1), xc = min(max(xi, 0), Wd - 1);
            float wt = (ddy ? wy : 1.f - wy) * (ddx ? wx : 1.f - wx);
            prA[u][c2] = yc * Wd + xc;
            prW[u][c2] = vc ? wt * msk : 0.f;
        }
        prOff[u] = tap * 64 + pxl;
        prV[u] = valid;
    }

    floatx4 acc[2][4];
#pragma unroll
    for (int c = 0; c < 2; c++)
#pragma unroll
        for (int ps = 0; ps < 4; ps++) acc[c][ps] = (floatx4){0.f, 0.f, 0.f, 0.f};

    const float* xab = xa + (size_t)b * Cc * HW;
    unsigned short* svf = &sv[0][0][0][0];

    for (int chunk = 0; chunk < 4; ++chunk) {
        __syncthreads();
#pragma unroll
        for (int u = 0; u < 3; u++) {
            if (prV[u]) {
                const int a0 = prA[u][0], a1 = prA[u][1], a2 = prA[u][2], a3 = prA[u][3];
                const float w0 = prW[u][0], w1 = prW[u][1], w2 = prW[u][2], w3 = prW[u][3];
#pragma unroll
                for (int cg = 0; cg < 4; cg++) {
                    const float* pb = xab + (size_t)(chunk * 32 + cg * 8) * HW;
                    // batch all 32 corner loads before any use
                    float l0[8], l1[8], l2[8], l3[8];
#pragma unroll
                    for (int ch = 0; ch < 8; ch++) {
                        const float* pc8 = pb + (size_t)ch * HW;
                        l0[ch] = pc8[a0];
                        l1[ch] = pc8[a1];
                        l2[ch] = pc8[a2];
                        l3[ch] = pc8[a3];
                    }
                    unsigned q[4];
#pragma unroll
                    for (int pair = 0; pair < 4; pair++) {
                        int e0 = 2 * pair, e1 = 2 * pair + 1;
                        float va = w0 * l0[e0] + w1 * l1[e0] + w2 * l2[e0] + w3 * l3[e0];
                        float vb = w0 * l0[e1] + w1 * l1[e1] + w2 * l2[e1] + w3 * l3[e1];
                        q[pair] = (unsigned)f2bf(va) | ((unsigned)f2bf(vb) << 16);
                    }
                    uint4 pk = make_uint4(q[0], q[1], q[2], q[3]);
                    *(uint4*)(svf + ((size_t)(cg * 576 + prOff[u]) << 3)) = pk;
                }
            }
        }
        __syncthreads();
#pragma unroll
        for (int tap = 0; tap < 9; ++tap) {
            short8v af[2];
#pragma unroll
            for (int c = 0; c < 2; c++) {
                int cot = wid * 2 + c;
                af[c] = *(const short8v*)(wpkO + ((((size_t)cot * 4 + chunk) * 9 + tap) * 64 + lane) * 8);
            }
            short8v bf[4];
#pragma unroll
            for (int ps = 0; ps < 4; ps++)
                bf[ps] = *(const short8v*)&sv[lhi][tap][ps * 16 + llo][0];
#pragma unroll
            for (int c = 0; c < 2; c++)
#pragma unroll
                for (int ps = 0; ps < 4; ps++)
                    acc[c][ps] = MFMA16(af[c], bf[ps], acc[c][ps]);
        }
    }

#pragma unroll
    for (int c = 0; c < 2; c++)
#pragma unroll
        for (int ps = 0; ps < 4; ps++)
#pragma unroll
            for (int reg = 0; reg < 4; reg++) {
                int co = (wid * 2 + c) * 16 + lhi * 4 + reg;
                int px = seg * 64 + ps * 16 + llo;
                out[((size_t)b * ldc + ch0 + co) * HW + h * Wd + px] = acc[c][ps][reg] + b_org[co];
            }
}

// ---- out = xa + lrelu(norm(dconv)) * (1 - attn) ----
__global__ void final_k(const float* __restrict__ rawAF, const float* __restrict__ xa,
                        const float* __restrict__ mu, const float* __restrict__ rsig,
                        float* __restrict__ outp) {
    size_t i4 = (size_t)blockIdx.x * BDIM + threadIdx.x;
    const size_t n4 = (size_t)BB * Cc * HW / 4;
    if (i4 >= n4) return;
    int plane = (int)(i4 / (HW / 4));
    int w4 = (int)(i4 % (HW / 4));
    int b = plane >> 7, c = plane & 127;
    const float4 a = *(const float4*)(rawAF + ((size_t)b * 256 + c) * HW + w4 * 4);
    float4 d = *(const float4*)(rawAF + ((size_t)b * 256 + 128 + c) * HW + w4 * 4);
    float4 xv = *(const float4*)(xa + (size_t)plane * HW + w4 * 4);
    float m = mu[plane], rs = rsig[plane];
    float4 o;
    float v;
    v = (d.x - m) * rs; v = v > 0.f ? v : 0.2f * v; o.x = xv.x + v * (1.f - a.x);
    v = (d.y - m) * rs; v = v > 0.f ? v : 0.2f * v; o.y = xv.y + v * (1.f - a.y);
    v = (d.z - m) * rs; v = v > 0.f ? v : 0.2f * v; o.z = xv.z + v * (1.f - a.z);
    v = (d.w - m) * rs; v = v > 0.f ? v : 0.2f * v; o.w = xv.w + v * (1.f - a.w);
    *(float4*)(outp + (size_t)plane * HW + w4 * 4) = o;
}

extern "C" void kernel_launch(void* const* d_in, const int* in_sizes, int n_in,
                              void* d_out, int out_size, void* d_ws, size_t ws_size,
                              hipStream_t stream) {
    const float* x      = (const float*)d_in[0];
    const float* w_attn = (const float*)d_in[1];
    const float* b_attn = (const float*)d_in[2];
    const float* w_feat = (const float*)d_in[3];
    const float* b_feat = (const float*)d_in[4];
    const float* w_org  = (const float*)d_in[5];
    const float* b_org  = (const float*)d_in[6];
    const float* w_off  = (const float*)d_in[7];
    const float* b_off  = (const float*)d_in[8];
    const float* w_mask = (const float*)d_in[9];
    const float* b_mask = (const float*)d_in[10];
    float* out = (float*)d_out;
    (void)in_sizes; (void)n_in; (void)out_size; (void)ws_size;

    float* ws = (float*)d_ws;
    size_t o = 0;
    float* rawAF = ws + o; o += (size_t)BB * 256 * HW;  // ch0-127: attn(sig); ch128-255: featRaw -> dconv
    float* xa    = ws + o; o += (size_t)BB * Cc * HW;
    float* offm  = ws + o; o += (size_t)BB * 32 * HW;
    unsigned short* wpkAF = (unsigned short*)(ws + o); o += 16 * 18432 / 2;
    unsigned short* wpkO  = (unsigned short*)(ws + o); o += 8 * 18432 / 2;
    unsigned short* wpkOM = (unsigned short*)(ws + o); o += 2 * 18432 / 2;
    float* bOM = ws + o; o += 32;
    float* mu1 = ws + o; o += 512;
    float* rs1 = ws + o; o += 512;
    float* mu2 = ws + o; o += 512;
    float* rs2 = ws + o; o += 512;

    repack_conv_k<<<(8 * 18432 + BDIM - 1) / BDIM, BDIM, 0, stream>>>(w_attn, wpkAF, 8, 128);
    repack_conv_k<<<(8 * 18432 + BDIM - 1) / BDIM, BDIM, 0, stream>>>(w_feat, wpkAF + 8 * 18432, 8, 128);
    repack_conv_k<<<(8 * 18432 + BDIM - 1) / BDIM, BDIM, 0, stream>>>(w_org, wpkO, 8, 128);
    repack_om_k<<<(2 * 18432 + BDIM - 1) / BDIM, BDIM, 0, stream>>>(w_off, w_mask, wpkOM);
    pack_bom_k<<<1, 32, 0, stream>>>(b_off, b_mask, bOM);

    convmf_k<4, 2><<<dim3(4, Hh, BB), BDIM, 0, stream>>>(
        x, wpkAF, b_attn, b_feat, 128, 128, rawAF, 256, 0);

    inorm_stats_k<<<BB * Cc, BDIM, 0, stream>>>(rawAF, mu1, rs1, 256, 128);

    const int n4 = BB * Cc * HW / 4;
    xattned_k<<<(n4 + BDIM - 1) / BDIM, BDIM, 0, stream>>>(rawAF, mu1, rs1, xa);

    convmf_k<2, 1><<<dim3(1, Hh, BB), BDIM, 0, stream>>>(
        xa, wpkOM, bOM, bOM, 32, 0, offm, 32, 0);

    deform_mfma_k<<<dim3(2, Hh, BB), BDIM, 0, stream>>>(
        xa, offm, wpkO, b_org, rawAF, 256, 128);

    inorm_stats_k<<<BB * Cc, BDIM, 0, stream>>>(rawAF, mu2, rs2, 256, 128);

    final_k<<<(n4 + BDIM - 1) / BDIM, BDIM, 0, stream>>>(rawAF, xa, mu2, rs2, out);
}

// Round 4
// 358.603 us; speedup vs baseline: 1.0035x; 1.0035x over previous
//
#include <hip/hip_runtime.h>
#include <math.h>

#define BDIM 256
constexpr int BB = 4, Cc = 128, Hh = 128, Wd = 128, HW = Hh * Wd;
constexpr float EPSv = 1e-5f;

typedef __attribute__((ext_vector_type(8))) short short8v;
typedef __attribute__((ext_vector_type(4))) float floatx4;

#define MFMA16(a, b, c) __builtin_amdgcn_mfma_f32_16x16x32_bf16((a), (b), (c), 0, 0, 0)

__device__ __forceinline__ float sigmoidf_(float v) { return 1.f / (1.f + __expf(-v)); }

__device__ __forceinline__ unsigned short f2bf(float f) {
    union { float f; unsigned u; } v; v.f = f;
    unsigned r = v.u + 0x7FFFu + ((v.u >> 16) & 1u);
    return (unsigned short)(r >> 16);
}

// ---- weight repack into per-lane MFMA fragment order ----
__global__ void repack_conv_k(const float* __restrict__ w, unsigned short* __restrict__ dst,
                              int ncot, int cout) {
    int idx = blockIdx.x * BDIM + threadIdx.x;
    int total = ncot * 4 * 9 * 64 * 8;
    if (idx >= total) return;
    int i = idx & 7;
    int lane = (idx >> 3) & 63;
    int tap = (idx >> 9) % 9;
    int chunk = (idx / (9 * 512)) & 3;
    int cot = idx / (4 * 9 * 512);
    int co = cot * 16 + (lane & 15);
    int ci = chunk * 32 + (lane >> 4) * 8 + i;
    float v = (co < cout) ? w[((size_t)co * Cc + ci) * 9 + tap] : 0.f;
    dst[idx] = f2bf(v);
}

__global__ void repack_om_k(const float* __restrict__ w_off, const float* __restrict__ w_mask,
                            unsigned short* __restrict__ dst) {
    int idx = blockIdx.x * BDIM + threadIdx.x;
    int total = 2 * 4 * 9 * 64 * 8;
    if (idx >= total) return;
    int i = idx & 7;
    int lane = (idx >> 3) & 63;
    int tap = (idx >> 9) % 9;
    int chunk = (idx / (9 * 512)) & 3;
    int cot = idx / (4 * 9 * 512);
    int co = cot * 16 + (lane & 15);
    int ci = chunk * 32 + (lane >> 4) * 8 + i;
    float v = 0.f;
    if (co < 18)      v = w_off[((size_t)co * Cc + ci) * 9 + tap];
    else if (co < 27) v = w_mask[((size_t)(co - 18) * Cc + ci) * 9 + tap];
    dst[idx] = f2bf(v);
}

__global__ void pack_bom_k(const float* __restrict__ b_off, const float* __restrict__ b_mask,
                           float* __restrict__ bom) {
    int i = threadIdx.x;
    if (i < 32) bom[i] = (i < 18) ? b_off[i] : (i < 27 ? b_mask[i - 18] : 0.f);
}

// ---- MFMA implicit-GEMM conv3x3 (pad=1) ----
template <int COTPB, int WCO>
__global__ __launch_bounds__(256) void convmf_k(
    const float* __restrict__ x, const unsigned short* __restrict__ wpk,
    const float* __restrict__ biasA, const float* __restrict__ biasB,
    int bsplit, int sigsplit,
    float* __restrict__ out, int ldc, int ch0) {
    constexpr int WPX = 4 / WCO;
    constexpr int PS = 8 / WPX;
    const int cb = blockIdx.x, h = blockIdx.y, b = blockIdx.z;
    const int t = threadIdx.x;
    const int lane = t & 63, llo = t & 15, lhi = (t >> 4) & 3;
    const int wid = t >> 6;
    const int wr = wid / WPX, wc = wid % WPX;

    __shared__ unsigned short xs[3][4][132][8];

    floatx4 acc[2][PS];
#pragma unroll
    for (int c = 0; c < 2; c++)
#pragma unroll
        for (int ps = 0; ps < PS; ps++) acc[c][ps] = (floatx4){0.f, 0.f, 0.f, 0.f};

    const float* xb = x + (size_t)b * Cc * HW;

    for (int chunk = 0; chunk < 4; ++chunk) {
        __syncthreads();
        for (int task = t; task < 3120; task += BDIM) {
            int j = task % 130;
            int rc = task / 130;
            int r = rc >> 3, ci4 = rc & 7;
            int hh = h + r - 1, col = j - 1;
            float v0 = 0.f, v1 = 0.f, v2 = 0.f, v3 = 0.f;
            if ((unsigned)hh < (unsigned)Hh && (unsigned)col < (unsigned)Wd) {
                const float* p = xb + (size_t)(chunk * 32 + ci4 * 4) * HW + hh * Wd + col;
                v0 = p[0]; v1 = p[HW]; v2 = p[2 * HW]; v3 = p[3 * HW];
            }
            ushort4 u;
            u.x = f2bf(v0); u.y = f2bf(v1); u.z = f2bf(v2); u.w = f2bf(v3);
            *(ushort4*)&xs[r][ci4 >> 1][j][(ci4 & 1) * 4] = u;
        }
        __syncthreads();
#pragma unroll
        for (int tap = 0; tap < 9; ++tap) {
            const int r = tap / 3, dx = tap % 3;
            short8v af[2];
#pragma unroll
            for (int c = 0; c < 2; c++) {
                int cot = cb * COTPB + wr * 2 + c;
                af[c] = *(const short8v*)(wpk + ((((size_t)cot * 4 + chunk) * 9 + tap) * 64 + lane) * 8);
            }
            short8v bf[PS];
#pragma unroll
            for (int ps = 0; ps < PS; ps++)
                bf[ps] = *(const short8v*)&xs[r][lhi][wc * (PS * 16) + ps * 16 + llo + dx][0];
#pragma unroll
            for (int c = 0; c < 2; c++)
#pragma unroll
                for (int ps = 0; ps < PS; ps++)
                    acc[c][ps] = MFMA16(af[c], bf[ps], acc[c][ps]);
        }
    }

    const int cbase = cb * (COTPB * 16);
    const float* bp = (cbase < bsplit) ? biasA : biasB;
    const int bshift = (cbase < bsplit) ? 0 : bsplit;
    const bool dosig = cbase < sigsplit;
#pragma unroll
    for (int c = 0; c < 2; c++)
#pragma unroll
        for (int ps = 0; ps < PS; ps++)
#pragma unroll
            for (int reg = 0; reg < 4; reg++) {
                int co = cbase + (wr * 2 + c) * 16 + lhi * 4 + reg;
                int px = wc * (PS * 16) + ps * 16 + llo;
                float v = acc[c][ps][reg] + bp[co - bshift];
                if (dosig) v = sigmoidf_(v);
                out[((size_t)b * ldc + ch0 + co) * HW + h * Wd + px] = v;
            }
}

// ---- instance-norm stats ----
__global__ __launch_bounds__(256) void inorm_stats_k(const float* __restrict__ src,
                                                     float* __restrict__ mu, float* __restrict__ rsig,
                                                     int chTot, int ch0) {
    const int bc = blockIdx.x;
    const int b = bc >> 7, c = bc & 127;
    const float4* p = (const float4*)(src + ((size_t)b * chTot + ch0 + c) * HW);
    float s = 0.f, s2 = 0.f;
    for (int i = threadIdx.x; i < HW / 4; i += BDIM) {
        float4 v = p[i];
        s += v.x + v.y + v.z + v.w;
        s2 += v.x * v.x + v.y * v.y + v.z * v.z + v.w * v.w;
    }
    __shared__ float ss[BDIM], sq[BDIM];
    int t = threadIdx.x;
    ss[t] = s; sq[t] = s2;
    __syncthreads();
    for (int off = BDIM / 2; off > 0; off >>= 1) {
        if (t < off) { ss[t] += ss[t + off]; sq[t] += sq[t + off]; }
        __syncthreads();
    }
    if (t == 0) {
        float m = ss[0] / HW;
        float var = sq[0] / HW - m * m;
        mu[bc] = m;
        rsig[bc] = rsqrtf(var + EPSv);
    }
}

// ---- xa = lrelu(norm(featRaw)) * attn, gridded like deform for XCD/L2 locality ----
__global__ __launch_bounds__(256) void xattned_k(const float* __restrict__ rawAF,
                                                 const float* __restrict__ mu,
                                                 const float* __restrict__ rsig,
                                                 float* __restrict__ xa) {
    const int seg = blockIdx.x, h = blockIdx.y, b = blockIdx.z;
    const int t = threadIdx.x;
    const int px4 = t & 15;   // 16 float4 = 64 px
    const int cl = t >> 4;    // 16 channels per pass
#pragma unroll
    for (int p = 0; p < 8; p++) {
        int c = p * 16 + cl;
        int plane = b * 128 + c;
        size_t pixo = (size_t)h * Wd + seg * 64 + px4 * 4;
        const float4 a = *(const float4*)(rawAF + ((size_t)b * 256 + c) * HW + pixo);
        float4 f = *(const float4*)(rawAF + ((size_t)b * 256 + 128 + c) * HW + pixo);
        float m = mu[plane], rs = rsig[plane];
        float4 o;
        float v;
        v = (f.x - m) * rs; v = v > 0.f ? v : 0.2f * v; o.x = v * a.x;
        v = (f.y - m) * rs; v = v > 0.f ? v : 0.2f * v; o.y = v * a.y;
        v = (f.z - m) * rs; v = v > 0.f ? v : 0.2f * v; o.z = v * a.z;
        v = (f.w - m) * rs; v = v > 0.f ? v : 0.2f * v; o.w = v * a.w;
        *(float4*)(xa + (size_t)plane * HW + pixo) = o;
    }
}

#define KEEPALIVE8(A) asm volatile("" :: "v"(A[0]), "v"(A[1]), "v"(A[2]), "v"(A[3]), \
                                        "v"(A[4]), "v"(A[5]), "v"(A[6]), "v"(A[7]))

// ---- deformable conv: batched-load gather (keep-alive forced) -> bf16 im2col LDS -> MFMA ----
__global__ __launch_bounds__(256, 4) void deform_mfma_k(
    const float* __restrict__ xa, const float* __restrict__ om,
    const unsigned short* __restrict__ wpkO, const float* __restrict__ b_org,
    float* __restrict__ out, int ldc, int ch0) {
    const int seg = blockIdx.x, h = blockIdx.y, b = blockIdx.z;
    const int t = threadIdx.x;
    const int lane = t & 63, llo = t & 15, lhi = (t >> 4) & 3;
    const int wid = t >> 6;

    __shared__ unsigned short sv[4][9][64][8];  // [cigrp][tap][px][ci8]

    int prA[3][4];
    float prW[3][4];
    int prOff[3];
    bool prV[3];

    const float* omb = om + (size_t)b * 32 * HW;
#pragma unroll
    for (int u = 0; u < 3; u++) {
        bool valid;
        int pc;
        if (u < 2) { valid = true; pc = t + u * 256; }
        else { valid = (t & 3) == 0; pc = 512 + (t >> 2); }
        int tap = pc >> 6, pxl = pc & 63;
        int ww = seg * 64 + pxl;
        int pix = h * Wd + ww;
        float dy = omb[(size_t)(2 * tap) * HW + pix];
        float dxv = omb[(size_t)(2 * tap + 1) * HW + pix];
        float msk = sigmoidf_(omb[(size_t)(18 + tap) * HW + pix]);
        float yy = dy + (float)(h + tap / 3 - 1);
        float xx = dxv + (float)(ww + tap % 3 - 1);
        float y0f = floorf(yy), x0f = floorf(xx);
        float wy = yy - y0f, wx = xx - x0f;
        int y0 = (int)y0f, x0 = (int)x0f;
#pragma unroll
        for (int c2 = 0; c2 < 4; c2++) {
            int ddy = c2 >> 1, ddx = c2 & 1;
            int yi = y0 + ddy, xi = x0 + ddx;
            bool vc = (yi >= 0) && (yi < Hh) && (xi >= 0) && (xi < Wd);
            int yc = min(max(yi, 0), Hh - 1), xc = min(max(xi, 0), Wd - 1);
            float wt = (ddy ? wy : 1.f - wy) * (ddx ? wx : 1.f - wx);
            prA[u][c2] = yc * Wd + xc;
            prW[u][c2] = vc ? wt * msk : 0.f;
        }
        prOff[u] = tap * 64 + pxl;
        prV[u] = valid;
    }

    floatx4 acc[2][4];
#pragma unroll
    for (int c = 0; c < 2; c++)
#pragma unroll
        for (int ps = 0; ps < 4; ps++) acc[c][ps] = (floatx4){0.f, 0.f, 0.f, 0.f};

    const float* xab = xa + (size_t)b * Cc * HW;
    unsigned short* svf = &sv[0][0][0][0];

    for (int chunk = 0; chunk < 4; ++chunk) {
        __syncthreads();
#pragma unroll
        for (int u = 0; u < 3; u++) {
            if (prV[u]) {
                const int a0 = prA[u][0], a1 = prA[u][1], a2 = prA[u][2], a3 = prA[u][3];
                const float w0 = prW[u][0], w1 = prW[u][1], w2 = prW[u][2], w3 = prW[u][3];
#pragma unroll
                for (int cg = 0; cg < 4; cg++) {
                    const float* pb = xab + (size_t)(chunk * 32 + cg * 8) * HW;
                    float l0[8], l1[8], l2[8], l3[8];
#pragma unroll
                    for (int ch = 0; ch < 8; ch++) {
                        const float* pc8 = pb + (size_t)ch * HW;
                        l0[ch] = pc8[a0];
                        l1[ch] = pc8[a1];
                        l2[ch] = pc8[a2];
                        l3[ch] = pc8[a3];
                    }
                    // force all 32 loads resident (issued back-to-back, <=2 waits)
                    KEEPALIVE8(l0); KEEPALIVE8(l1);
                    KEEPALIVE8(l2); KEEPALIVE8(l3);
                    unsigned q[4];
#pragma unroll
                    for (int pair = 0; pair < 4; pair++) {
                        int e0 = 2 * pair, e1 = 2 * pair + 1;
                        float va = w0 * l0[e0] + w1 * l1[e0] + w2 * l2[e0] + w3 * l3[e0];
                        float vb = w0 * l0[e1] + w1 * l1[e1] + w2 * l2[e1] + w3 * l3[e1];
                        q[pair] = (unsigned)f2bf(va) | ((unsigned)f2bf(vb) << 16);
                    }
                    uint4 pk = make_uint4(q[0], q[1], q[2], q[3]);
                    *(uint4*)(svf + ((size_t)(cg * 576 + prOff[u]) << 3)) = pk;
                }
            }
        }
        __syncthreads();
#pragma unroll
        for (int tap = 0; tap < 9; ++tap) {
            short8v af[2];
#pragma unroll
            for (int c = 0; c < 2; c++) {
                int cot = wid * 2 + c;
                af[c] = *(const short8v*)(wpkO + ((((size_t)cot * 4 + chunk) * 9 + tap) * 64 + lane) * 8);
            }
            short8v bf[4];
#pragma unroll
            for (int ps = 0; ps < 4; ps++)
                bf[ps] = *(const short8v*)&sv[lhi][tap][ps * 16 + llo][0];
#pragma unroll
            for (int c = 0; c < 2; c++)
#pragma unroll
                for (int ps = 0; ps < 4; ps++)
                    acc[c][ps] = MFMA16(af[c], bf[ps], acc[c][ps]);
        }
    }

#pragma unroll
    for (int c = 0; c < 2; c++)
#pragma unroll
        for (int ps = 0; ps < 4; ps++)
#pragma unroll
            for (int reg = 0; reg < 4; reg++) {
                int co = (wid * 2 + c) * 16 + lhi * 4 + reg;
                int px = seg * 64 + ps * 16 + llo;
                out[((size_t)b * ldc + ch0 + co) * HW + h * Wd + px] = acc[c][ps][reg] + b_org[co];
            }
}

// ---- out = xa + lrelu(norm(dconv)) * (1 - attn) ----
__global__ void final_k(const float* __restrict__ rawAF, const float* __restrict__ xa,
                        const float* __restrict__ mu, const float* __restrict__ rsig,
                        float* __restrict__ outp) {
    size_t i4 = (size_t)blockIdx.x * BDIM + threadIdx.x;
    const size_t n4 = (size_t)BB * Cc * HW / 4;
    if (i4 >= n4) return;
    int plane = (int)(i4 / (HW / 4));
    int w4 = (int)(i4 % (HW / 4));
    int b = plane >> 7, c = plane & 127;
    const float4 a = *(const float4*)(rawAF + ((size_t)b * 256 + c) * HW + w4 * 4);
    float4 d = *(const float4*)(rawAF + ((size_t)b * 256 + 128 + c) * HW + w4 * 4);
    float4 xv = *(const float4*)(xa + (size_t)plane * HW + w4 * 4);
    float m = mu[plane], rs = rsig[plane];
    float4 o;
    float v;
    v = (d.x - m) * rs; v = v > 0.f ? v : 0.2f * v; o.x = xv.x + v * (1.f - a.x);
    v = (d.y - m) * rs; v = v > 0.f ? v : 0.2f * v; o.y = xv.y + v * (1.f - a.y);
    v = (d.z - m) * rs; v = v > 0.f ? v : 0.2f * v; o.z = xv.z + v * (1.f - a.z);
    v = (d.w - m) * rs; v = v > 0.f ? v : 0.2f * v; o.w = xv.w + v * (1.f - a.w);
    *(float4*)(outp + (size_t)plane * HW + w4 * 4) = o;
}

extern "C" void kernel_launch(void* const* d_in, const int* in_sizes, int n_in,
                              void* d_out, int out_size, void* d_ws, size_t ws_size,
                              hipStream_t stream) {
    const float* x      = (const float*)d_in[0];
    const float* w_attn = (const float*)d_in[1];
    const float* b_attn = (const float*)d_in[2];
    const float* w_feat = (const float*)d_in[3];
    const float* b_feat = (const float*)d_in[4];
    const float* w_org  = (const float*)d_in[5];
    const float* b_org  = (const float*)d_in[6];
    const float* w_off  = (const float*)d_in[7];
    const float* b_off  = (const float*)d_in[8];
    const float* w_mask = (const float*)d_in[9];
    const float* b_mask = (const float*)d_in[10];
    float* out = (float*)d_out;
    (void)in_sizes; (void)n_in; (void)out_size; (void)ws_size;

    float* ws = (float*)d_ws;
    size_t o = 0;
    float* rawAF = ws + o; o += (size_t)BB * 256 * HW;  // ch0-127: attn(sig); ch128-255: featRaw -> dconv
    float* xa    = ws + o; o += (size_t)BB * Cc * HW;
    float* offm  = ws + o; o += (size_t)BB * 32 * HW;
    unsigned short* wpkAF = (unsigned short*)(ws + o); o += 16 * 18432 / 2;
    unsigned short* wpkO  = (unsigned short*)(ws + o); o += 8 * 18432 / 2;
    unsigned short* wpkOM = (unsigned short*)(ws + o); o += 2 * 18432 / 2;
    float* bOM = ws + o; o += 32;
    float* mu1 = ws + o; o += 512;
    float* rs1 = ws + o; o += 512;
    float* mu2 = ws + o; o += 512;
    float* rs2 = ws + o; o += 512;

    repack_conv_k<<<(8 * 18432 + BDIM - 1) / BDIM, BDIM, 0, stream>>>(w_attn, wpkAF, 8, 128);
    repack_conv_k<<<(8 * 18432 + BDIM - 1) / BDIM, BDIM, 0, stream>>>(w_feat, wpkAF + 8 * 18432, 8, 128);
    repack_conv_k<<<(8 * 18432 + BDIM - 1) / BDIM, BDIM, 0, stream>>>(w_org, wpkO, 8, 128);
    repack_om_k<<<(2 * 18432 + BDIM - 1) / BDIM, BDIM, 0, stream>>>(w_off, w_mask, wpkOM);
    pack_bom_k<<<1, 32, 0, stream>>>(b_off, b_mask, bOM);

    convmf_k<4, 2><<<dim3(4, Hh, BB), BDIM, 0, stream>>>(
        x, wpkAF, b_attn, b_feat, 128, 128, rawAF, 256, 0);

    inorm_stats_k<<<BB * Cc, BDIM, 0, stream>>>(rawAF, mu1, rs1, 256, 128);

    xattned_k<<<dim3(2, Hh, BB), BDIM, 0, stream>>>(rawAF, mu1, rs1, xa);

    convmf_k<2, 1><<<dim3(1, Hh, BB), BDIM, 0, stream>>>(
        xa, wpkOM, bOM, bOM, 32, 0, offm, 32, 0);

    deform_mfma_k<<<dim3(2, Hh, BB), BDIM, 0, stream>>>(
        xa, offm, wpkO, b_org, rawAF, 256, 128);

    inorm_stats_k<<<BB * Cc, BDIM, 0, stream>>>(rawAF, mu2, rs2, 256, 128);

    const int n4 = BB * Cc * HW / 4;
    final_k<<<(n4 + BDIM - 1) / BDIM, BDIM, 0, stream>>>(rawAF, xa, mu2, rs2, out);
}

// Round 5
// 278.808 us; speedup vs baseline: 1.2906x; 1.2862x over previous
//
#include <hip/hip_runtime.h>
#include <math.h>

#define BDIM 256
constexpr int BB = 4, Cc = 128, Hh = 128, Wd = 128, HW = Hh * Wd;
constexpr float EPSv = 1e-5f;

typedef __attribute__((ext_vector_type(8))) short short8v;
typedef __attribute__((ext_vector_type(4))) float floatx4;

#define MFMA16(a, b, c) __builtin_amdgcn_mfma_f32_16x16x32_bf16((a), (b), (c), 0, 0, 0)

__device__ __forceinline__ float sigmoidf_(float v) { return 1.f / (1.f + __expf(-v)); }

__device__ __forceinline__ unsigned short f2bf(float f) {
    union { float f; unsigned u; } v; v.f = f;
    unsigned r = v.u + 0x7FFFu + ((v.u >> 16) & 1u);
    return (unsigned short)(r >> 16);
}

// packed f32x2 -> bf16x2 (RNE)
__device__ __forceinline__ unsigned cvtpk(float a, float b) {
    unsigned r;
    asm("v_cvt_pk_bf16_f32 %0, %1, %2" : "=v"(r) : "v"(a), "v"(b));
    return r;
}
__device__ __forceinline__ float bflo(unsigned u) { union { unsigned u; float f; } v; v.u = u << 16; return v.f; }
__device__ __forceinline__ float bfhi(unsigned u) { union { unsigned u; float f; } v; v.u = u & 0xFFFF0000u; return v.f; }

// ---- weight repack into per-lane MFMA fragment order ----
__global__ void repack_conv_k(const float* __restrict__ w, unsigned short* __restrict__ dst,
                              int ncot, int cout) {
    int idx = blockIdx.x * BDIM + threadIdx.x;
    int total = ncot * 4 * 9 * 64 * 8;
    if (idx >= total) return;
    int i = idx & 7;
    int lane = (idx >> 3) & 63;
    int tap = (idx >> 9) % 9;
    int chunk = (idx / (9 * 512)) & 3;
    int cot = idx / (4 * 9 * 512);
    int co = cot * 16 + (lane & 15);
    int ci = chunk * 32 + (lane >> 4) * 8 + i;
    float v = (co < cout) ? w[((size_t)co * Cc + ci) * 9 + tap] : 0.f;
    dst[idx] = f2bf(v);
}

__global__ void repack_om_k(const float* __restrict__ w_off, const float* __restrict__ w_mask,
                            unsigned short* __restrict__ dst) {
    int idx = blockIdx.x * BDIM + threadIdx.x;
    int total = 2 * 4 * 9 * 64 * 8;
    if (idx >= total) return;
    int i = idx & 7;
    int lane = (idx >> 3) & 63;
    int tap = (idx >> 9) % 9;
    int chunk = (idx / (9 * 512)) & 3;
    int cot = idx / (4 * 9 * 512);
    int co = cot * 16 + (lane & 15);
    int ci = chunk * 32 + (lane >> 4) * 8 + i;
    float v = 0.f;
    if (co < 18)      v = w_off[((size_t)co * Cc + ci) * 9 + tap];
    else if (co < 27) v = w_mask[((size_t)(co - 18) * Cc + ci) * 9 + tap];
    dst[idx] = f2bf(v);
}

__global__ void pack_bom_k(const float* __restrict__ b_off, const float* __restrict__ b_mask,
                           float* __restrict__ bom) {
    int i = threadIdx.x;
    if (i < 32) bom[i] = (i < 18) ? b_off[i] : (i < 27 ? b_mask[i - 18] : 0.f);
}

// ---- MFMA implicit-GEMM conv3x3 (pad=1) ----
template <int COTPB, int WCO>
__global__ __launch_bounds__(256) void convmf_k(
    const float* __restrict__ x, const unsigned short* __restrict__ wpk,
    const float* __restrict__ biasA, const float* __restrict__ biasB,
    int bsplit, int sigsplit,
    float* __restrict__ out, int ldc, int ch0) {
    constexpr int WPX = 4 / WCO;
    constexpr int PS = 8 / WPX;
    const int cb = blockIdx.x, h = blockIdx.y, b = blockIdx.z;
    const int t = threadIdx.x;
    const int lane = t & 63, llo = t & 15, lhi = (t >> 4) & 3;
    const int wid = t >> 6;
    const int wr = wid / WPX, wc = wid % WPX;

    __shared__ unsigned short xs[3][4][132][8];

    floatx4 acc[2][PS];
#pragma unroll
    for (int c = 0; c < 2; c++)
#pragma unroll
        for (int ps = 0; ps < PS; ps++) acc[c][ps] = (floatx4){0.f, 0.f, 0.f, 0.f};

    const float* xb = x + (size_t)b * Cc * HW;

    for (int chunk = 0; chunk < 4; ++chunk) {
        __syncthreads();
        for (int task = t; task < 3120; task += BDIM) {
            int j = task % 130;
            int rc = task / 130;
            int r = rc >> 3, ci4 = rc & 7;
            int hh = h + r - 1, col = j - 1;
            float v0 = 0.f, v1 = 0.f, v2 = 0.f, v3 = 0.f;
            if ((unsigned)hh < (unsigned)Hh && (unsigned)col < (unsigned)Wd) {
                const float* p = xb + (size_t)(chunk * 32 + ci4 * 4) * HW + hh * Wd + col;
                v0 = p[0]; v1 = p[HW]; v2 = p[2 * HW]; v3 = p[3 * HW];
            }
            ushort4 u;
            u.x = f2bf(v0); u.y = f2bf(v1); u.z = f2bf(v2); u.w = f2bf(v3);
            *(ushort4*)&xs[r][ci4 >> 1][j][(ci4 & 1) * 4] = u;
        }
        __syncthreads();
#pragma unroll
        for (int tap = 0; tap < 9; ++tap) {
            const int r = tap / 3, dx = tap % 3;
            short8v af[2];
#pragma unroll
            for (int c = 0; c < 2; c++) {
                int cot = cb * COTPB + wr * 2 + c;
                af[c] = *(const short8v*)(wpk + ((((size_t)cot * 4 + chunk) * 9 + tap) * 64 + lane) * 8);
            }
            short8v bf[PS];
#pragma unroll
            for (int ps = 0; ps < PS; ps++)
                bf[ps] = *(const short8v*)&xs[r][lhi][wc * (PS * 16) + ps * 16 + llo + dx][0];
#pragma unroll
            for (int c = 0; c < 2; c++)
#pragma unroll
                for (int ps = 0; ps < PS; ps++)
                    acc[c][ps] = MFMA16(af[c], bf[ps], acc[c][ps]);
        }
    }

    const int cbase = cb * (COTPB * 16);
    const float* bp = (cbase < bsplit) ? biasA : biasB;
    const int bshift = (cbase < bsplit) ? 0 : bsplit;
    const bool dosig = cbase < sigsplit;
#pragma unroll
    for (int c = 0; c < 2; c++)
#pragma unroll
        for (int ps = 0; ps < PS; ps++)
#pragma unroll
            for (int reg = 0; reg < 4; reg++) {
                int co = cbase + (wr * 2 + c) * 16 + lhi * 4 + reg;
                int px = wc * (PS * 16) + ps * 16 + llo;
                float v = acc[c][ps][reg] + bp[co - bshift];
                if (dosig) v = sigmoidf_(v);
                out[((size_t)b * ldc + ch0 + co) * HW + h * Wd + px] = v;
            }
}

// ---- instance-norm stats ----
__global__ __launch_bounds__(256) void inorm_stats_k(const float* __restrict__ src,
                                                     float* __restrict__ mu, float* __restrict__ rsig,
                                                     int chTot, int ch0) {
    const int bc = blockIdx.x;
    const int b = bc >> 7, c = bc & 127;
    const float4* p = (const float4*)(src + ((size_t)b * chTot + ch0 + c) * HW);
    float s = 0.f, s2 = 0.f;
    for (int i = threadIdx.x; i < HW / 4; i += BDIM) {
        float4 v = p[i];
        s += v.x + v.y + v.z + v.w;
        s2 += v.x * v.x + v.y * v.y + v.z * v.z + v.w * v.w;
    }
    __shared__ float ss[BDIM], sq[BDIM];
    int t = threadIdx.x;
    ss[t] = s; sq[t] = s2;
    __syncthreads();
    for (int off = BDIM / 2; off > 0; off >>= 1) {
        if (t < off) { ss[t] += ss[t + off]; sq[t] += sq[t + off]; }
        __syncthreads();
    }
    if (t == 0) {
        float m = ss[0] / HW;
        float var = sq[0] / HW - m * m;
        mu[bc] = m;
        rsig[bc] = rsqrtf(var + EPSv);
    }
}

// ---- xa = lrelu(norm(featRaw)) * attn, gridded like deform for XCD/L2 locality ----
__global__ __launch_bounds__(256) void xattned_k(const float* __restrict__ rawAF,
                                                 const float* __restrict__ mu,
                                                 const float* __restrict__ rsig,
                                                 float* __restrict__ xa) {
    const int seg = blockIdx.x, h = blockIdx.y, b = blockIdx.z;
    const int t = threadIdx.x;
    const int px4 = t & 15;
    const int cl = t >> 4;
#pragma unroll
    for (int p = 0; p < 8; p++) {
        int c = p * 16 + cl;
        int plane = b * 128 + c;
        size_t pixo = (size_t)h * Wd + seg * 64 + px4 * 4;
        const float4 a = *(const float4*)(rawAF + ((size_t)b * 256 + c) * HW + pixo);
        float4 f = *(const float4*)(rawAF + ((size_t)b * 256 + 128 + c) * HW + pixo);
        float m = mu[plane], rs = rsig[plane];
        float4 o;
        float v;
        v = (f.x - m) * rs; v = v > 0.f ? v : 0.2f * v; o.x = v * a.x;
        v = (f.y - m) * rs; v = v > 0.f ? v : 0.2f * v; o.y = v * a.y;
        v = (f.z - m) * rs; v = v > 0.f ? v : 0.2f * v; o.z = v * a.z;
        v = (f.w - m) * rs; v = v > 0.f ? v : 0.2f * v; o.w = v * a.w;
        *(float4*)(xa + (size_t)plane * HW + pixo) = o;
    }
}

// ---- deformable conv: LDS-tile gather -> bf16 im2col LDS -> MFMA ----
// Tile: rows h-2..h+3 (6), cols seg*64-2..+69 (72), 32ch as 16 bf16-pairs. 63KB LDS total.
__global__ __launch_bounds__(256, 2) void deform_mfma_k(
    const float* __restrict__ xa, const float* __restrict__ om,
    const unsigned short* __restrict__ wpkO, const float* __restrict__ b_org,
    float* __restrict__ out, int ldc, int ch0) {
    const int seg = blockIdx.x, h = blockIdx.y, b = blockIdx.z;
    const int t = threadIdx.x;
    const int lane = t & 63, llo = t & 15, lhi = (t >> 4) & 3;
    const int wid = t >> 6;
    const int cb = seg * 64;

    __shared__ unsigned short sv[4][9][64][8];  // [cigrp][tap][px][ci8]  36864 B
    __shared__ unsigned xt[16 * 6 * 72];        // [c2][row][col] bf16-pairs  27648 B

    // per-thread gather tables. units 0..575 = tap*64+px.
    int prA[3][4];    // global fallback pixel addrs
    float prW[3][4];  // corner weights (mask*valid folded)
    int prT0[3];      // tile dword base (ty0*72+tx0)
    int prOff[3];
    bool prV[3], prOK[3];

    const float* omb = om + (size_t)b * 32 * HW;
#pragma unroll
    for (int u = 0; u < 3; u++) {
        bool valid;
        int pc;
        if (u < 2) { valid = true; pc = t + u * 256; }
        else { valid = (t & 3) == 0; pc = 512 + (t >> 2); }
        int tap = pc >> 6, pxl = pc & 63;
        int ww = cb + pxl;
        int pix = h * Wd + ww;
        float dy = omb[(size_t)(2 * tap) * HW + pix];
        float dxv = omb[(size_t)(2 * tap + 1) * HW + pix];
        float msk = sigmoidf_(omb[(size_t)(18 + tap) * HW + pix]);
        float yy = dy + (float)(h + tap / 3 - 1);
        float xx = dxv + (float)(ww + tap % 3 - 1);
        float y0f = floorf(yy), x0f = floorf(xx);
        float wy = yy - y0f, wx = xx - x0f;
        int y0 = (int)y0f, x0 = (int)x0f;
#pragma unroll
        for (int c2 = 0; c2 < 4; c2++) {
            int ddy = c2 >> 1, ddx = c2 & 1;
            int yi = y0 + ddy, xi = x0 + ddx;
            bool vc = (yi >= 0) && (yi < Hh) && (xi >= 0) && (xi < Wd);
            int yc = min(max(yi, 0), Hh - 1), xc = min(max(xi, 0), Wd - 1);
            float wt = (ddy ? wy : 1.f - wy) * (ddx ? wx : 1.f - wx);
            prA[u][c2] = yc * Wd + xc;
            prW[u][c2] = vc ? wt * msk : 0.f;
        }
        int ty0 = y0 - (h - 2);
        int tx0 = x0 - (cb - 2);
        prOK[u] = ((unsigned)ty0 <= 4u) && ((unsigned)tx0 <= 70u);
        prT0[u] = ty0 * 72 + tx0;
        prOff[u] = tap * 64 + pxl;
        prV[u] = valid;
    }

    floatx4 acc[2][4];
#pragma unroll
    for (int c = 0; c < 2; c++)
#pragma unroll
        for (int ps = 0; ps < 4; ps++) acc[c][ps] = (floatx4){0.f, 0.f, 0.f, 0.f};

    const float* xab = xa + (size_t)b * Cc * HW;
    unsigned short* svf = &sv[0][0][0][0];

    for (int chunk = 0; chunk < 4; ++chunk) {
        __syncthreads();
        // ---- stage 6x72x32ch window as bf16 pairs into xt ----
        for (int task = t; task < 1728; task += BDIM) {
            int qc = task % 18;
            int row = (task / 18) % 6;
            int c2 = task / 108;
            int r = h - 2 + row;
            int cxb = cb - 2 + qc * 4;
            const float* p0 = xab + (size_t)(chunk * 32 + 2 * c2) * HW + r * Wd;
            const float* p1 = p0 + HW;
            bool rok = (unsigned)r < (unsigned)Hh;
            unsigned q[4];
#pragma unroll
            for (int j = 0; j < 4; j++) {
                int cX = cxb + j;
                bool ok = rok && ((unsigned)cX < (unsigned)Wd);
                float lo = ok ? p0[cX] : 0.f;
                float hi = ok ? p1[cX] : 0.f;
                q[j] = cvtpk(lo, hi);
            }
            *(uint4*)&xt[(c2 * 6 + row) * 72 + qc * 4] = make_uint4(q[0], q[1], q[2], q[3]);
        }
        __syncthreads();
        // ---- gather from LDS tile -> sv ----
#pragma unroll
        for (int u = 0; u < 3; u++) {
            if (!prV[u]) continue;
            const float w0 = prW[u][0], w1 = prW[u][1], w2 = prW[u][2], w3 = prW[u][3];
            if (prOK[u]) {
                const int t0 = prT0[u];
#pragma unroll
                for (int cg = 0; cg < 4; cg++) {
                    unsigned q[4];
#pragma unroll
                    for (int j = 0; j < 4; j++) {
                        int d = (cg * 4 + j) * 432 + t0;
                        unsigned c00 = xt[d], c01 = xt[d + 1];
                        unsigned c10 = xt[d + 72], c11 = xt[d + 73];
                        float va = w0 * bflo(c00) + w1 * bflo(c01) + w2 * bflo(c10) + w3 * bflo(c11);
                        float vb = w0 * bfhi(c00) + w1 * bfhi(c01) + w2 * bfhi(c10) + w3 * bfhi(c11);
                        q[j] = cvtpk(va, vb);
                    }
                    *(uint4*)(svf + ((size_t)(cg * 576 + prOff[u]) << 3)) =
                        make_uint4(q[0], q[1], q[2], q[3]);
                }
            } else {  // rare fallback: offsets escaped the tile
                const int a0 = prA[u][0], a1 = prA[u][1], a2 = prA[u][2], a3 = prA[u][3];
#pragma unroll
                for (int cg = 0; cg < 4; cg++) {
                    const float* pb = xab + (size_t)(chunk * 32 + cg * 8) * HW;
                    unsigned q[4];
#pragma unroll
                    for (int pair = 0; pair < 4; pair++) {
                        const float* p0 = pb + (size_t)(2 * pair) * HW;
                        const float* p1 = pb + (size_t)(2 * pair + 1) * HW;
                        float va = w0 * p0[a0] + w1 * p0[a1] + w2 * p0[a2] + w3 * p0[a3];
                        float vb = w0 * p1[a0] + w1 * p1[a1] + w2 * p1[a2] + w3 * p1[a3];
                        q[pair] = cvtpk(va, vb);
                    }
                    *(uint4*)(svf + ((size_t)(cg * 576 + prOff[u]) << 3)) =
                        make_uint4(q[0], q[1], q[2], q[3]);
                }
            }
        }
        __syncthreads();
        // ---- MFMA contraction ----
#pragma unroll
        for (int tap = 0; tap < 9; ++tap) {
            short8v af[2];
#pragma unroll
            for (int c = 0; c < 2; c++) {
                int cot = wid * 2 + c;
                af[c] = *(const short8v*)(wpkO + ((((size_t)cot * 4 + chunk) * 9 + tap) * 64 + lane) * 8);
            }
            short8v bf[4];
#pragma unroll
            for (int ps = 0; ps < 4; ps++)
                bf[ps] = *(const short8v*)&sv[lhi][tap][ps * 16 + llo][0];
#pragma unroll
            for (int c = 0; c < 2; c++)
#pragma unroll
                for (int ps = 0; ps < 4; ps++)
                    acc[c][ps] = MFMA16(af[c], bf[ps], acc[c][ps]);
        }
    }

#pragma unroll
    for (int c = 0; c < 2; c++)
#pragma unroll
        for (int ps = 0; ps < 4; ps++)
#pragma unroll
            for (int reg = 0; reg < 4; reg++) {
                int co = (wid * 2 + c) * 16 + lhi * 4 + reg;
                int px = cb + ps * 16 + llo;
                out[((size_t)b * ldc + ch0 + co) * HW + h * Wd + px] = acc[c][ps][reg] + b_org[co];
            }
}

// ---- out = xa + lrelu(norm(dconv)) * (1 - attn) ----
__global__ void final_k(const float* __restrict__ rawAF, const float* __restrict__ xa,
                        const float* __restrict__ mu, const float* __restrict__ rsig,
                        float* __restrict__ outp) {
    size_t i4 = (size_t)blockIdx.x * BDIM + threadIdx.x;
    const size_t n4 = (size_t)BB * Cc * HW / 4;
    if (i4 >= n4) return;
    int plane = (int)(i4 / (HW / 4));
    int w4 = (int)(i4 % (HW / 4));
    int b = plane >> 7, c = plane & 127;
    const float4 a = *(const float4*)(rawAF + ((size_t)b * 256 + c) * HW + w4 * 4);
    float4 d = *(const float4*)(rawAF + ((size_t)b * 256 + 128 + c) * HW + w4 * 4);
    float4 xv = *(const float4*)(xa + (size_t)plane * HW + w4 * 4);
    float m = mu[plane], rs = rsig[plane];
    float4 o;
    float v;
    v = (d.x - m) * rs; v = v > 0.f ? v : 0.2f * v; o.x = xv.x + v * (1.f - a.x);
    v = (d.y - m) * rs; v = v > 0.f ? v : 0.2f * v; o.y = xv.y + v * (1.f - a.y);
    v = (d.z - m) * rs; v = v > 0.f ? v : 0.2f * v; o.z = xv.z + v * (1.f - a.z);
    v = (d.w - m) * rs; v = v > 0.f ? v : 0.2f * v; o.w = xv.w + v * (1.f - a.w);
    *(float4*)(outp + (size_t)plane * HW + w4 * 4) = o;
}

extern "C" void kernel_launch(void* const* d_in, const int* in_sizes, int n_in,
                              void* d_out, int out_size, void* d_ws, size_t ws_size,
                              hipStream_t stream) {
    const float* x      = (const float*)d_in[0];
    const float* w_attn = (const float*)d_in[1];
    const float* b_attn = (const float*)d_in[2];
    const float* w_feat = (const float*)d_in[3];
    const float* b_feat = (const float*)d_in[4];
    const float* w_org  = (const float*)d_in[5];
    const float* b_org  = (const float*)d_in[6];
    const float* w_off  = (const float*)d_in[7];
    const float* b_off  = (const float*)d_in[8];
    const float* w_mask = (const float*)d_in[9];
    const float* b_mask = (const float*)d_in[10];
    float* out = (float*)d_out;
    (void)in_sizes; (void)n_in; (void)out_size; (void)ws_size;

    float* ws = (float*)d_ws;
    size_t o = 0;
    float* rawAF = ws + o; o += (size_t)BB * 256 * HW;  // ch0-127: attn(sig); ch128-255: featRaw -> dconv
    float* xa    = ws + o; o += (size_t)BB * Cc * HW;
    float* offm  = ws + o; o += (size_t)BB * 32 * HW;
    unsigned short* wpkAF = (unsigned short*)(ws + o); o += 16 * 18432 / 2;
    unsigned short* wpkO  = (unsigned short*)(ws + o); o += 8 * 18432 / 2;
    unsigned short* wpkOM = (unsigned short*)(ws + o); o += 2 * 18432 / 2;
    float* bOM = ws + o; o += 32;
    float* mu1 = ws + o; o += 512;
    float* rs1 = ws + o; o += 512;
    float* mu2 = ws + o; o += 512;
    float* rs2 = ws + o; o += 512;

    repack_conv_k<<<(8 * 18432 + BDIM - 1) / BDIM, BDIM, 0, stream>>>(w_attn, wpkAF, 8, 128);
    repack_conv_k<<<(8 * 18432 + BDIM - 1) / BDIM, BDIM, 0, stream>>>(w_feat, wpkAF + 8 * 18432, 8, 128);
    repack_conv_k<<<(8 * 18432 + BDIM - 1) / BDIM, BDIM, 0, stream>>>(w_org, wpkO, 8, 128);
    repack_om_k<<<(2 * 18432 + BDIM - 1) / BDIM, BDIM, 0, stream>>>(w_off, w_mask, wpkOM);
    pack_bom_k<<<1, 32, 0, stream>>>(b_off, b_mask, bOM);

    convmf_k<4, 2><<<dim3(4, Hh, BB), BDIM, 0, stream>>>(
        x, wpkAF, b_attn, b_feat, 128, 128, rawAF, 256, 0);

    inorm_stats_k<<<BB * Cc, BDIM, 0, stream>>>(rawAF, mu1, rs1, 256, 128);

    xattned_k<<<dim3(2, Hh, BB), BDIM, 0, stream>>>(rawAF, mu1, rs1, xa);

    convmf_k<2, 1><<<dim3(1, Hh, BB), BDIM, 0, stream>>>(
        xa, wpkOM, bOM, bOM, 32, 0, offm, 32, 0);

    deform_mfma_k<<<dim3(2, Hh, BB), BDIM, 0, stream>>>(
        xa, offm, wpkO, b_org, rawAF, 256, 128);

    inorm_stats_k<<<BB * Cc, BDIM, 0, stream>>>(rawAF, mu2, rs2, 256, 128);

    const int n4 = BB * Cc * HW / 4;
    final_k<<<(n4 + BDIM - 1) / BDIM, BDIM, 0, stream>>>(rawAF, xa, mu2, rs2, out);
}

// Round 6
// 245.302 us; speedup vs baseline: 1.4669x; 1.1366x over previous
//
#include <hip/hip_runtime.h>
#include <math.h>

#define BDIM 256
constexpr int BB = 4, Cc = 128, Hh = 128, Wd = 128, HW = Hh * Wd;
constexpr float EPSv = 1e-5f;

typedef __attribute__((ext_vector_type(8))) short short8v;
typedef __attribute__((ext_vector_type(4))) float floatx4;

#define MFMA16(a, b, c) __builtin_amdgcn_mfma_f32_16x16x32_bf16((a), (b), (c), 0, 0, 0)

__device__ __forceinline__ float sigmoidf_(float v) { return 1.f / (1.f + __expf(-v)); }

__device__ __forceinline__ unsigned short f2bf(float f) {
    union { float f; unsigned u; } v; v.f = f;
    unsigned r = v.u + 0x7FFFu + ((v.u >> 16) & 1u);
    return (unsigned short)(r >> 16);
}

// packed f32x2 -> bf16x2 (RNE)
__device__ __forceinline__ unsigned cvtpk(float a, float b) {
    unsigned r;
    asm("v_cvt_pk_bf16_f32 %0, %1, %2" : "=v"(r) : "v"(a), "v"(b));
    return r;
}
__device__ __forceinline__ float bflo(unsigned u) { union { unsigned u; float f; } v; v.u = u << 16; return v.f; }
__device__ __forceinline__ float bfhi(unsigned u) { union { unsigned u; float f; } v; v.u = u & 0xFFFF0000u; return v.f; }

// LDS-only barrier: does NOT drain vmcnt, so in-flight global prefetch survives.
__device__ __forceinline__ void barrier_lgkm() {
    asm volatile("s_waitcnt lgkmcnt(0)" ::: "memory");
    __builtin_amdgcn_s_barrier();
}

// ---- weight repack into per-lane MFMA fragment order ----
__global__ void repack_conv_k(const float* __restrict__ w, unsigned short* __restrict__ dst,
                              int ncot, int cout) {
    int idx = blockIdx.x * BDIM + threadIdx.x;
    int total = ncot * 4 * 9 * 64 * 8;
    if (idx >= total) return;
    int i = idx & 7;
    int lane = (idx >> 3) & 63;
    int tap = (idx >> 9) % 9;
    int chunk = (idx / (9 * 512)) & 3;
    int cot = idx / (4 * 9 * 512);
    int co = cot * 16 + (lane & 15);
    int ci = chunk * 32 + (lane >> 4) * 8 + i;
    float v = (co < cout) ? w[((size_t)co * Cc + ci) * 9 + tap] : 0.f;
    dst[idx] = f2bf(v);
}

__global__ void repack_om_k(const float* __restrict__ w_off, const float* __restrict__ w_mask,
                            unsigned short* __restrict__ dst) {
    int idx = blockIdx.x * BDIM + threadIdx.x;
    int total = 2 * 4 * 9 * 64 * 8;
    if (idx >= total) return;
    int i = idx & 7;
    int lane = (idx >> 3) & 63;
    int tap = (idx >> 9) % 9;
    int chunk = (idx / (9 * 512)) & 3;
    int cot = idx / (4 * 9 * 512);
    int co = cot * 16 + (lane & 15);
    int ci = chunk * 32 + (lane >> 4) * 8 + i;
    float v = 0.f;
    if (co < 18)      v = w_off[((size_t)co * Cc + ci) * 9 + tap];
    else if (co < 27) v = w_mask[((size_t)(co - 18) * Cc + ci) * 9 + tap];
    dst[idx] = f2bf(v);
}

__global__ void pack_bom_k(const float* __restrict__ b_off, const float* __restrict__ b_mask,
                           float* __restrict__ bom) {
    int i = threadIdx.x;
    if (i < 32) bom[i] = (i < 18) ? b_off[i] : (i < 27 ? b_mask[i - 18] : 0.f);
}

// ---- MFMA implicit-GEMM conv3x3 (pad=1) ----
template <int COTPB, int WCO>
__global__ __launch_bounds__(256) void convmf_k(
    const float* __restrict__ x, const unsigned short* __restrict__ wpk,
    const float* __restrict__ biasA, const float* __restrict__ biasB,
    int bsplit, int sigsplit,
    float* __restrict__ out, int ldc, int ch0) {
    constexpr int WPX = 4 / WCO;
    constexpr int PS = 8 / WPX;
    const int cb = blockIdx.x, h = blockIdx.y, b = blockIdx.z;
    const int t = threadIdx.x;
    const int lane = t & 63, llo = t & 15, lhi = (t >> 4) & 3;
    const int wid = t >> 6;
    const int wr = wid / WPX, wc = wid % WPX;

    __shared__ unsigned short xs[3][4][132][8];

    floatx4 acc[2][PS];
#pragma unroll
    for (int c = 0; c < 2; c++)
#pragma unroll
        for (int ps = 0; ps < PS; ps++) acc[c][ps] = (floatx4){0.f, 0.f, 0.f, 0.f};

    const float* xb = x + (size_t)b * Cc * HW;

    for (int chunk = 0; chunk < 4; ++chunk) {
        __syncthreads();
        for (int task = t; task < 3120; task += BDIM) {
            int j = task % 130;
            int rc = task / 130;
            int r = rc >> 3, ci4 = rc & 7;
            int hh = h + r - 1, col = j - 1;
            float v0 = 0.f, v1 = 0.f, v2 = 0.f, v3 = 0.f;
            if ((unsigned)hh < (unsigned)Hh && (unsigned)col < (unsigned)Wd) {
                const float* p = xb + (size_t)(chunk * 32 + ci4 * 4) * HW + hh * Wd + col;
                v0 = p[0]; v1 = p[HW]; v2 = p[2 * HW]; v3 = p[3 * HW];
            }
            ushort4 u;
            u.x = f2bf(v0); u.y = f2bf(v1); u.z = f2bf(v2); u.w = f2bf(v3);
            *(ushort4*)&xs[r][ci4 >> 1][j][(ci4 & 1) * 4] = u;
        }
        __syncthreads();
#pragma unroll
        for (int tap = 0; tap < 9; ++tap) {
            const int r = tap / 3, dx = tap % 3;
            short8v af[2];
#pragma unroll
            for (int c = 0; c < 2; c++) {
                int cot = cb * COTPB + wr * 2 + c;
                af[c] = *(const short8v*)(wpk + ((((size_t)cot * 4 + chunk) * 9 + tap) * 64 + lane) * 8);
            }
            short8v bf[PS];
#pragma unroll
            for (int ps = 0; ps < PS; ps++)
                bf[ps] = *(const short8v*)&xs[r][lhi][wc * (PS * 16) + ps * 16 + llo + dx][0];
#pragma unroll
            for (int c = 0; c < 2; c++)
#pragma unroll
                for (int ps = 0; ps < PS; ps++)
                    acc[c][ps] = MFMA16(af[c], bf[ps], acc[c][ps]);
        }
    }

    const int cbase = cb * (COTPB * 16);
    const float* bp = (cbase < bsplit) ? biasA : biasB;
    const int bshift = (cbase < bsplit) ? 0 : bsplit;
    const bool dosig = cbase < sigsplit;
#pragma unroll
    for (int c = 0; c < 2; c++)
#pragma unroll
        for (int ps = 0; ps < PS; ps++)
#pragma unroll
            for (int reg = 0; reg < 4; reg++) {
                int co = cbase + (wr * 2 + c) * 16 + lhi * 4 + reg;
                int px = wc * (PS * 16) + ps * 16 + llo;
                float v = acc[c][ps][reg] + bp[co - bshift];
                if (dosig) v = sigmoidf_(v);
                out[((size_t)b * ldc + ch0 + co) * HW + h * Wd + px] = v;
            }
}

// ---- instance-norm stats ----
__global__ __launch_bounds__(256) void inorm_stats_k(const float* __restrict__ src,
                                                     float* __restrict__ mu, float* __restrict__ rsig,
                                                     int chTot, int ch0) {
    const int bc = blockIdx.x;
    const int b = bc >> 7, c = bc & 127;
    const float4* p = (const float4*)(src + ((size_t)b * chTot + ch0 + c) * HW);
    float s = 0.f, s2 = 0.f;
    for (int i = threadIdx.x; i < HW / 4; i += BDIM) {
        float4 v = p[i];
        s += v.x + v.y + v.z + v.w;
        s2 += v.x * v.x + v.y * v.y + v.z * v.z + v.w * v.w;
    }
    __shared__ float ss[BDIM], sq[BDIM];
    int t = threadIdx.x;
    ss[t] = s; sq[t] = s2;
    __syncthreads();
    for (int off = BDIM / 2; off > 0; off >>= 1) {
        if (t < off) { ss[t] += ss[t + off]; sq[t] += sq[t + off]; }
        __syncthreads();
    }
    if (t == 0) {
        float m = ss[0] / HW;
        float var = sq[0] / HW - m * m;
        mu[bc] = m;
        rsig[bc] = rsqrtf(var + EPSv);
    }
}

// ---- xa = lrelu(norm(featRaw)) * attn, gridded like deform for XCD/L2 locality ----
__global__ __launch_bounds__(256) void xattned_k(const float* __restrict__ rawAF,
                                                 const float* __restrict__ mu,
                                                 const float* __restrict__ rsig,
                                                 float* __restrict__ xa) {
    const int seg = blockIdx.x, h = blockIdx.y, b = blockIdx.z;
    const int t = threadIdx.x;
    const int px4 = t & 15;
    const int cl = t >> 4;
#pragma unroll
    for (int p = 0; p < 8; p++) {
        int c = p * 16 + cl;
        int plane = b * 128 + c;
        size_t pixo = (size_t)h * Wd + seg * 64 + px4 * 4;
        const float4 a = *(const float4*)(rawAF + ((size_t)b * 256 + c) * HW + pixo);
        float4 f = *(const float4*)(rawAF + ((size_t)b * 256 + 128 + c) * HW + pixo);
        float m = mu[plane], rs = rsig[plane];
        float4 o;
        float v;
        v = (f.x - m) * rs; v = v > 0.f ? v : 0.2f * v; o.x = v * a.x;
        v = (f.y - m) * rs; v = v > 0.f ? v : 0.2f * v; o.y = v * a.y;
        v = (f.z - m) * rs; v = v > 0.f ? v : 0.2f * v; o.z = v * a.z;
        v = (f.w - m) * rs; v = v > 0.f ? v : 0.2f * v; o.w = v * a.w;
        *(float4*)(xa + (size_t)plane * HW + pixo) = o;
    }
}

// ---- deformable conv: prefetch-pipelined LDS-tile gather -> bf16 im2col -> MFMA ----
// xt: [c2(8)][6][72] bf16-pair dwords for a 16-channel half  (13824 B)
// sv: [cg(4)][tap(9)][px(64)][ci8]                            (36864 B)  -> 3 blocks/CU
__global__ __launch_bounds__(256, 3) void deform_mfma_k(
    const float* __restrict__ xa, const float* __restrict__ om,
    const unsigned short* __restrict__ wpkO, const float* __restrict__ b_org,
    float* __restrict__ out, int ldc, int ch0) {
    const int seg = blockIdx.x, h = blockIdx.y, b = blockIdx.z;
    const int t = threadIdx.x;
    const int lane = t & 63, llo = t & 15, lhi = (t >> 4) & 3;
    const int wid = t >> 6;
    const int cb = seg * 64;

    __shared__ unsigned short sv[4][9][64][8];
    __shared__ unsigned xt[8 * 6 * 72];

    // per-thread gather tables. units 0..575 = tap*64+px.
    int prA[3][4];
    float prW[3][4];
    int prT0[3];
    int prOff[3];
    bool prV[3], prOK[3];

    const float* omb = om + (size_t)b * 32 * HW;
#pragma unroll
    for (int u = 0; u < 3; u++) {
        bool valid;
        int pc;
        if (u < 2) { valid = true; pc = t + u * 256; }
        else { valid = (t & 3) == 0; pc = 512 + (t >> 2); }
        int tap = pc >> 6, pxl = pc & 63;
        int ww = cb + pxl;
        int pix = h * Wd + ww;
        float dy = omb[(size_t)(2 * tap) * HW + pix];
        float dxv = omb[(size_t)(2 * tap + 1) * HW + pix];
        float msk = sigmoidf_(omb[(size_t)(18 + tap) * HW + pix]);
        float yy = dy + (float)(h + tap / 3 - 1);
        float xx = dxv + (float)(ww + tap % 3 - 1);
        float y0f = floorf(yy), x0f = floorf(xx);
        float wy = yy - y0f, wx = xx - x0f;
        int y0 = (int)y0f, x0 = (int)x0f;
#pragma unroll
        for (int c2 = 0; c2 < 4; c2++) {
            int ddy = c2 >> 1, ddx = c2 & 1;
            int yi = y0 + ddy, xi = x0 + ddx;
            bool vc = (yi >= 0) && (yi < Hh) && (xi >= 0) && (xi < Wd);
            int yc = min(max(yi, 0), Hh - 1), xc = min(max(xi, 0), Wd - 1);
            float wt = (ddy ? wy : 1.f - wy) * (ddx ? wx : 1.f - wx);
            prA[u][c2] = yc * Wd + xc;
            prW[u][c2] = vc ? wt * msk : 0.f;
        }
        int ty0 = y0 - (h - 2);
        int tx0 = x0 - (cb - 2);
        prOK[u] = ((unsigned)ty0 <= 4u) && ((unsigned)tx0 <= 70u);
        prT0[u] = ty0 * 72 + tx0;
        prOff[u] = tap * 64 + pxl;
        prV[u] = valid;
    }

    floatx4 acc[2][4];
#pragma unroll
    for (int c = 0; c < 2; c++)
#pragma unroll
        for (int ps = 0; ps < 4; ps++) acc[c][ps] = (floatx4){0.f, 0.f, 0.f, 0.f};

    const float* xab = xa + (size_t)b * Cc * HW;
    unsigned short* svf = &sv[0][0][0][0];

    // prefetch registers for one 16-channel half: 4 tasks x 8 channels
    float R[4][8];

    // issue stage loads for half-index nc (0..7), cbase = nc*16
    auto issue_stage = [&](int nc) {
        const int cbase = nc * 16;
#pragma unroll
        for (int it = 0; it < 4; it++) {
            int task = t + it * 256;
            if (task < 864) {
                int col = task % 72;
                int rg = task / 72;
                int row = rg % 6, grp = rg / 6;
                int r = h - 2 + row, cX = cb - 2 + col;
                int rc = min(max(r, 0), Hh - 1), cc = min(max(cX, 0), Wd - 1);
                const float* p = xab + (size_t)(cbase + grp * 8) * HW + rc * Wd + cc;
#pragma unroll
                for (int j = 0; j < 8; j++) R[it][j] = p[(size_t)j * HW];
            }
        }
    };

    issue_stage(0);

    for (int chunk = 0; chunk < 4; ++chunk) {
#pragma unroll
        for (int half = 0; half < 2; ++half) {
            barrier_lgkm();  // previous xt readers done (no vmcnt drain)
            // write prefetched half into xt (compiler inserts vmcnt waits)
#pragma unroll
            for (int it = 0; it < 4; it++) {
                int task = t + it * 256;
                if (task < 864) {
                    int col = task % 72;
                    int rg = task / 72;
                    int row = rg % 6, grp = rg / 6;
                    int r = h - 2 + row, cX = cb - 2 + col;
                    bool ok = ((unsigned)r < (unsigned)Hh) && ((unsigned)cX < (unsigned)Wd);
                    int cell = row * 72 + col;
#pragma unroll
                    for (int k = 0; k < 4; k++) {
                        float lo = ok ? R[it][2 * k] : 0.f;
                        float hi = ok ? R[it][2 * k + 1] : 0.f;
                        xt[(grp * 4 + k) * 432 + cell] = cvtpk(lo, hi);
                    }
                }
            }
            // prefetch the NEXT half while gather below runs
            int nc = chunk * 2 + half + 1;
            if (nc < 8) issue_stage(nc);
            barrier_lgkm();  // xt visible
            // gather from xt -> sv (cg = half*2 .. half*2+1)
#pragma unroll
            for (int u = 0; u < 3; u++) {
                if (!prV[u]) continue;
                const float w0 = prW[u][0], w1 = prW[u][1], w2 = prW[u][2], w3 = prW[u][3];
                if (prOK[u]) {
                    const int d0 = prT0[u];
                    unsigned q[8];
#pragma unroll
                    for (int c2 = 0; c2 < 8; c2++) {
                        unsigned c00 = xt[c2 * 432 + d0];
                        unsigned c01 = xt[c2 * 432 + d0 + 1];
                        unsigned c10 = xt[c2 * 432 + d0 + 72];
                        unsigned c11 = xt[c2 * 432 + d0 + 73];
                        float va = w0 * bflo(c00) + w1 * bflo(c01) + w2 * bflo(c10) + w3 * bflo(c11);
                        float vb = w0 * bfhi(c00) + w1 * bfhi(c01) + w2 * bfhi(c10) + w3 * bfhi(c11);
                        q[c2] = cvtpk(va, vb);
                    }
                    *(uint4*)(svf + ((size_t)((half * 2 + 0) * 576 + prOff[u]) << 3)) =
                        make_uint4(q[0], q[1], q[2], q[3]);
                    *(uint4*)(svf + ((size_t)((half * 2 + 1) * 576 + prOff[u]) << 3)) =
                        make_uint4(q[4], q[5], q[6], q[7]);
                } else {  // rare: offsets escaped the tile -> direct global
                    const int a0 = prA[u][0], a1 = prA[u][1], a2 = prA[u][2], a3 = prA[u][3];
                    const float* pb = xab + (size_t)(chunk * 32 + half * 16) * HW;
#pragma unroll
                    for (int cg2 = 0; cg2 < 2; cg2++) {
                        unsigned q[4];
#pragma unroll
                        for (int pair = 0; pair < 4; pair++) {
                            const float* p0 = pb + (size_t)(cg2 * 8 + 2 * pair) * HW;
                            const float* p1 = p0 + HW;
                            float va = w0 * p0[a0] + w1 * p0[a1] + w2 * p0[a2] + w3 * p0[a3];
                            float vb = w0 * p1[a0] + w1 * p1[a1] + w2 * p1[a2] + w3 * p1[a3];
                            q[pair] = cvtpk(va, vb);
                        }
                        *(uint4*)(svf + ((size_t)((half * 2 + cg2) * 576 + prOff[u]) << 3)) =
                            make_uint4(q[0], q[1], q[2], q[3]);
                    }
                }
            }
        }
        barrier_lgkm();  // sv complete
        // ---- MFMA contraction for this chunk ----
#pragma unroll
        for (int tap = 0; tap < 9; ++tap) {
            short8v af[2];
#pragma unroll
            for (int c = 0; c < 2; c++) {
                int cot = wid * 2 + c;
                af[c] = *(const short8v*)(wpkO + ((((size_t)cot * 4 + chunk) * 9 + tap) * 64 + lane) * 8);
            }
            short8v bf[4];
#pragma unroll
            for (int ps = 0; ps < 4; ps++)
                bf[ps] = *(const short8v*)&sv[lhi][tap][ps * 16 + llo][0];
#pragma unroll
            for (int c = 0; c < 2; c++)
#pragma unroll
                for (int ps = 0; ps < 4; ps++)
                    acc[c][ps] = MFMA16(af[c], bf[ps], acc[c][ps]);
        }
    }

#pragma unroll
    for (int c = 0; c < 2; c++)
#pragma unroll
        for (int ps = 0; ps < 4; ps++)
#pragma unroll
            for (int reg = 0; reg < 4; reg++) {
                int co = (wid * 2 + c) * 16 + lhi * 4 + reg;
                int px = cb + ps * 16 + llo;
                out[((size_t)b * ldc + ch0 + co) * HW + h * Wd + px] = acc[c][ps][reg] + b_org[co];
            }
}

// ---- out = xa + lrelu(norm(dconv)) * (1 - attn) ----
__global__ void final_k(const float* __restrict__ rawAF, const float* __restrict__ xa,
                        const float* __restrict__ mu, const float* __restrict__ rsig,
                        float* __restrict__ outp) {
    size_t i4 = (size_t)blockIdx.x * BDIM + threadIdx.x;
    const size_t n4 = (size_t)BB * Cc * HW / 4;
    if (i4 >= n4) return;
    int plane = (int)(i4 / (HW / 4));
    int w4 = (int)(i4 % (HW / 4));
    int b = plane >> 7, c = plane & 127;
    const float4 a = *(const float4*)(rawAF + ((size_t)b * 256 + c) * HW + w4 * 4);
    float4 d = *(const float4*)(rawAF + ((size_t)b * 256 + 128 + c) * HW + w4 * 4);
    float4 xv = *(const float4*)(xa + (size_t)plane * HW + w4 * 4);
    float m = mu[plane], rs = rsig[plane];
    float4 o;
    float v;
    v = (d.x - m) * rs; v = v > 0.f ? v : 0.2f * v; o.x = xv.x + v * (1.f - a.x);
    v = (d.y - m) * rs; v = v > 0.f ? v : 0.2f * v; o.y = xv.y + v * (1.f - a.y);
    v = (d.z - m) * rs; v = v > 0.f ? v : 0.2f * v; o.z = xv.z + v * (1.f - a.z);
    v = (d.w - m) * rs; v = v > 0.f ? v : 0.2f * v; o.w = xv.w + v * (1.f - a.w);
    *(float4*)(outp + (size_t)plane * HW + w4 * 4) = o;
}

extern "C" void kernel_launch(void* const* d_in, const int* in_sizes, int n_in,
                              void* d_out, int out_size, void* d_ws, size_t ws_size,
                              hipStream_t stream) {
    const float* x      = (const float*)d_in[0];
    const float* w_attn = (const float*)d_in[1];
    const float* b_attn = (const float*)d_in[2];
    const float* w_feat = (const float*)d_in[3];
    const float* b_feat = (const float*)d_in[4];
    const float* w_org  = (const float*)d_in[5];
    const float* b_org  = (const float*)d_in[6];
    const float* w_off  = (const float*)d_in[7];
    const float* b_off  = (const float*)d_in[8];
    const float* w_mask = (const float*)d_in[9];
    const float* b_mask = (const float*)d_in[10];
    float* out = (float*)d_out;
    (void)in_sizes; (void)n_in; (void)out_size; (void)ws_size;

    float* ws = (float*)d_ws;
    size_t o = 0;
    float* rawAF = ws + o; o += (size_t)BB * 256 * HW;  // ch0-127: attn(sig); ch128-255: featRaw -> dconv
    float* xa    = ws + o; o += (size_t)BB * Cc * HW;
    float* offm  = ws + o; o += (size_t)BB * 32 * HW;
    unsigned short* wpkAF = (unsigned short*)(ws + o); o += 16 * 18432 / 2;
    unsigned short* wpkO  = (unsigned short*)(ws + o); o += 8 * 18432 / 2;
    unsigned short* wpkOM = (unsigned short*)(ws + o); o += 2 * 18432 / 2;
    float* bOM = ws + o; o += 32;
    float* mu1 = ws + o; o += 512;
    float* rs1 = ws + o; o += 512;
    float* mu2 = ws + o; o += 512;
    float* rs2 = ws + o; o += 512;

    repack_conv_k<<<(8 * 18432 + BDIM - 1) / BDIM, BDIM, 0, stream>>>(w_attn, wpkAF, 8, 128);
    repack_conv_k<<<(8 * 18432 + BDIM - 1) / BDIM, BDIM, 0, stream>>>(w_feat, wpkAF + 8 * 18432, 8, 128);
    repack_conv_k<<<(8 * 18432 + BDIM - 1) / BDIM, BDIM, 0, stream>>>(w_org, wpkO, 8, 128);
    repack_om_k<<<(2 * 18432 + BDIM - 1) / BDIM, BDIM, 0, stream>>>(w_off, w_mask, wpkOM);
    pack_bom_k<<<1, 32, 0, stream>>>(b_off, b_mask, bOM);

    convmf_k<4, 2><<<dim3(4, Hh, BB), BDIM, 0, stream>>>(
        x, wpkAF, b_attn, b_feat, 128, 128, rawAF, 256, 0);

    inorm_stats_k<<<BB * Cc, BDIM, 0, stream>>>(rawAF, mu1, rs1, 256, 128);

    xattned_k<<<dim3(2, Hh, BB), BDIM, 0, stream>>>(rawAF, mu1, rs1, xa);

    convmf_k<2, 1><<<dim3(1, Hh, BB), BDIM, 0, stream>>>(
        xa, wpkOM, bOM, bOM, 32, 0, offm, 32, 0);

    deform_mfma_k<<<dim3(2, Hh, BB), BDIM, 0, stream>>>(
        xa, offm, wpkO, b_org, rawAF, 256, 128);

    inorm_stats_k<<<BB * Cc, BDIM, 0, stream>>>(rawAF, mu2, rs2, 256, 128);

    const int n4 = BB * Cc * HW / 4;
    final_k<<<(n4 + BDIM - 1) / BDIM, BDIM, 0, stream>>>(rawAF, xa, mu2, rs2, out);
}

// Round 7
// 234.901 us; speedup vs baseline: 1.5319x; 1.0443x over previous
//
#include <hip/hip_runtime.h>
#include <math.h>

#define BDIM 256
constexpr int BB = 4, Cc = 128, Hh = 128, Wd = 128, HW = Hh * Wd;
constexpr float EPSv = 1e-5f;

typedef __attribute__((ext_vector_type(8))) short short8v;
typedef __attribute__((ext_vector_type(4))) float floatx4;

#define MFMA16(a, b, c) __builtin_amdgcn_mfma_f32_16x16x32_bf16((a), (b), (c), 0, 0, 0)

__device__ __forceinline__ float sigmoidf_(float v) { return 1.f / (1.f + __expf(-v)); }

__device__ __forceinline__ unsigned short f2bf(float f) {
    union { float f; unsigned u; } v; v.f = f;
    unsigned r = v.u + 0x7FFFu + ((v.u >> 16) & 1u);
    return (unsigned short)(r >> 16);
}

__device__ __forceinline__ unsigned cvtpk(float a, float b) {
    unsigned r;
    asm("v_cvt_pk_bf16_f32 %0, %1, %2" : "=v"(r) : "v"(a), "v"(b));
    return r;
}
__device__ __forceinline__ float bflo(unsigned u) { union { unsigned u; float f; } v; v.u = u << 16; return v.f; }
__device__ __forceinline__ float bfhi(unsigned u) { union { unsigned u; float f; } v; v.u = u & 0xFFFF0000u; return v.f; }

// LDS-only barrier: does NOT drain vmcnt, so in-flight global prefetch survives.
__device__ __forceinline__ void barrier_lgkm() {
    asm volatile("s_waitcnt lgkmcnt(0)" ::: "memory");
    __builtin_amdgcn_s_barrier();
}

// ---- weight repack into per-lane MFMA fragment order ----
__global__ void repack_conv_k(const float* __restrict__ w, unsigned short* __restrict__ dst,
                              int ncot, int cout) {
    int idx = blockIdx.x * BDIM + threadIdx.x;
    int total = ncot * 4 * 9 * 64 * 8;
    if (idx >= total) return;
    int i = idx & 7;
    int lane = (idx >> 3) & 63;
    int tap = (idx >> 9) % 9;
    int chunk = (idx / (9 * 512)) & 3;
    int cot = idx / (4 * 9 * 512);
    int co = cot * 16 + (lane & 15);
    int ci = chunk * 32 + (lane >> 4) * 8 + i;
    float v = (co < cout) ? w[((size_t)co * Cc + ci) * 9 + tap] : 0.f;
    dst[idx] = f2bf(v);
}

__global__ void repack_om_k(const float* __restrict__ w_off, const float* __restrict__ w_mask,
                            unsigned short* __restrict__ dst) {
    int idx = blockIdx.x * BDIM + threadIdx.x;
    int total = 2 * 4 * 9 * 64 * 8;
    if (idx >= total) return;
    int i = idx & 7;
    int lane = (idx >> 3) & 63;
    int tap = (idx >> 9) % 9;
    int chunk = (idx / (9 * 512)) & 3;
    int cot = idx / (4 * 9 * 512);
    int co = cot * 16 + (lane & 15);
    int ci = chunk * 32 + (lane >> 4) * 8 + i;
    float v = 0.f;
    if (co < 18)      v = w_off[((size_t)co * Cc + ci) * 9 + tap];
    else if (co < 27) v = w_mask[((size_t)(co - 18) * Cc + ci) * 9 + tap];
    dst[idx] = f2bf(v);
}

__global__ void pack_bom_k(const float* __restrict__ b_off, const float* __restrict__ b_mask,
                           float* __restrict__ bom) {
    int i = threadIdx.x;
    if (i < 32) bom[i] = (i < 18) ? b_off[i] : (i < 27 ? b_mask[i - 18] : 0.f);
}

// ---- MFMA implicit-GEMM conv3x3 (pad=1), prefetch-pipelined, multi-row ----
// COTPB cot-tiles (16co each) per block, WCO cot-groups among 4 waves, ROWS out rows.
// Per half-chunk (16 ci): stage-prefetch into regs -> write LDS after lgkm barrier.
// Weight frags for chunk prefetched into regs one half early (barrier-protected).
template <int COTPB, int WCO, int ROWS, bool SWZ>
__global__ __launch_bounds__(256, 2) void conv2_k(
    const float* __restrict__ x, const unsigned short* __restrict__ wpk,
    const float* __restrict__ biasA, const float* __restrict__ biasB,
    int bsplit, int sigsplit,
    float* __restrict__ out, int ldc, int ch0) {
    constexpr int WPX = 4 / WCO;      // px groups among waves
    constexpr int PXW = 128 / WPX;    // px per wave
    constexpr int PS = PXW / 16;      // px subtiles per wave
    constexpr int SR = ROWS + 2;      // staged rows
    constexpr int NT = SR * 130 * 4;  // stage tasks per half-chunk (4ch units)
    constexpr int ITERS = (NT + 255) / 256;
    constexpr int HB = 128 / ROWS;    // h-blocks

    const int t = threadIdx.x;
    const int lane = t & 63, llo = t & 15, lhi = (t >> 4) & 3;
    const int wid = t >> 6;
    const int wr = wid / WPX, wc = wid % WPX;

    int cbi, h0, b;
    if (SWZ) {
        // group 4 cb-blocks of same (h,b) onto one XCD (n%8 = XCD assumption)
        int n = blockIdx.x;
        int xcd = n & 7, j = n >> 3;
        int g = (j >> 2) * 8 + xcd;
        cbi = j & 3;
        h0 = (g % HB) * ROWS;
        b = g / HB;
    } else {
        cbi = 0;
        h0 = ((int)blockIdx.x % HB) * ROWS;
        b = (int)blockIdx.x / HB;
    }
    const int cotbase = cbi * COTPB + wr * 2;

    __shared__ unsigned short xs[SR][4][132][8];

    floatx4 acc[2][ROWS][PS];
#pragma unroll
    for (int c = 0; c < 2; c++)
#pragma unroll
        for (int row = 0; row < ROWS; row++)
#pragma unroll
            for (int ps = 0; ps < PS; ps++) acc[c][row][ps] = (floatx4){0.f, 0.f, 0.f, 0.f};

    const float* xb = x + (size_t)b * Cc * HW;

    float R[ITERS][4];
    short8v afr[9][2];

    auto issueR = [&](int hf) {
        const int cibase = (hf >> 1) * 32 + (hf & 1) * 16;
#pragma unroll
        for (int it = 0; it < ITERS; it++) {
            int task = t + it * 256;
            if (task < NT) {
                int col = task % 130;
                int rest = task / 130;
                int row = rest % SR, grp = rest / SR;
                int r = h0 - 1 + row, cX = col - 1;
                int rc = min(max(r, 0), Hh - 1), cc = min(max(cX, 0), Wd - 1);
                const float* p = xb + (size_t)(cibase + grp * 4) * HW + rc * Wd + cc;
#pragma unroll
                for (int j = 0; j < 4; j++) R[it][j] = p[(size_t)j * HW];
            }
        }
    };

    issueR(0);

    for (int hf = 0; hf < 8; ++hf) {
        const int chunk = hf >> 1, hs = hf & 1;
        barrier_lgkm();  // previous readers of xs pair hs are done
        // write prefetched stage regs into xs (compiler waits R's vmcnt here,
        // which also drains the older afr loads before the MFMA below)
#pragma unroll
        for (int it = 0; it < ITERS; it++) {
            int task = t + it * 256;
            if (task < NT) {
                int col = task % 130;
                int rest = task / 130;
                int row = rest % SR, grp = rest / SR;
                int r = h0 - 1 + row, cX = col - 1;
                bool ok = ((unsigned)r < (unsigned)Hh) && ((unsigned)cX < (unsigned)Wd);
                ushort4 u;
                u.x = f2bf(ok ? R[it][0] : 0.f);
                u.y = f2bf(ok ? R[it][1] : 0.f);
                u.z = f2bf(ok ? R[it][2] : 0.f);
                u.w = f2bf(ok ? R[it][3] : 0.f);
                *(ushort4*)&xs[row][hs * 2 + (grp >> 1)][col][(grp & 1) * 4] = u;
            }
        }
        if (hs == 0) {
            // prefetch this chunk's weight frags (consumed after next barrier)
#pragma unroll
            for (int tap = 0; tap < 9; tap++)
#pragma unroll
                for (int c = 0; c < 2; c++)
                    afr[tap][c] = *(const short8v*)(wpk +
                        ((((size_t)(cotbase + c) * 4 + chunk) * 9 + tap) * 64 + lane) * 8);
        }
        if (hf < 7) issueR(hf + 1);  // prefetch next half's x
        barrier_lgkm();  // xs visible
        if (hs == 1) {
            // ---- MFMA for this chunk ----
#pragma unroll
            for (int tap = 0; tap < 9; ++tap) {
                const int r = tap / 3, dx = tap % 3;
#pragma unroll
                for (int row = 0; row < ROWS; row++) {
                    short8v bf[PS];
#pragma unroll
                    for (int ps = 0; ps < PS; ps++)
                        bf[ps] = *(const short8v*)&xs[row + r][lhi][wc * PXW + ps * 16 + llo + dx][0];
#pragma unroll
                    for (int c = 0; c < 2; c++)
#pragma unroll
                        for (int ps = 0; ps < PS; ps++)
                            acc[c][row][ps] = MFMA16(afr[tap][c], bf[ps], acc[c][row][ps]);
                }
            }
        }
    }

    const int cbase = cbi * (COTPB * 16);
    const float* bp = (cbase < bsplit) ? biasA : biasB;
    const int bshift = (cbase < bsplit) ? 0 : bsplit;
    const bool dosig = cbase < sigsplit;
#pragma unroll
    for (int c = 0; c < 2; c++)
#pragma unroll
        for (int row = 0; row < ROWS; row++)
#pragma unroll
            for (int ps = 0; ps < PS; ps++)
#pragma unroll
                for (int reg = 0; reg < 4; reg++) {
                    int co = cbase + (wr * 2 + c) * 16 + lhi * 4 + reg;
                    int px = wc * PXW + ps * 16 + llo;
                    float v = acc[c][row][ps][reg] + bp[co - bshift];
                    if (dosig) v = sigmoidf_(v);
                    out[((size_t)b * ldc + ch0 + co) * HW + (h0 + row) * Wd + px] = v;
                }
}

// ---- instance-norm stats ----
__global__ __launch_bounds__(256) void inorm_stats_k(const float* __restrict__ src,
                                                     float* __restrict__ mu, float* __restrict__ rsig,
                                                     int chTot, int ch0) {
    const int bc = blockIdx.x;
    const int b = bc >> 7, c = bc & 127;
    const float4* p = (const float4*)(src + ((size_t)b * chTot + ch0 + c) * HW);
    float s = 0.f, s2 = 0.f;
    for (int i = threadIdx.x; i < HW / 4; i += BDIM) {
        float4 v = p[i];
        s += v.x + v.y + v.z + v.w;
        s2 += v.x * v.x + v.y * v.y + v.z * v.z + v.w * v.w;
    }
    __shared__ float ss[BDIM], sq[BDIM];
    int t = threadIdx.x;
    ss[t] = s; sq[t] = s2;
    __syncthreads();
    for (int off = BDIM / 2; off > 0; off >>= 1) {
        if (t < off) { ss[t] += ss[t + off]; sq[t] += sq[t + off]; }
        __syncthreads();
    }
    if (t == 0) {
        float m = ss[0] / HW;
        float var = sq[0] / HW - m * m;
        mu[bc] = m;
        rsig[bc] = rsqrtf(var + EPSv);
    }
}

// ---- xa = lrelu(norm(featRaw)) * attn ----
__global__ __launch_bounds__(256) void xattned_k(const float* __restrict__ rawAF,
                                                 const float* __restrict__ mu,
                                                 const float* __restrict__ rsig,
                                                 float* __restrict__ xa) {
    const int seg = blockIdx.x, h = blockIdx.y, b = blockIdx.z;
    const int t = threadIdx.x;
    const int px4 = t & 15;
    const int cl = t >> 4;
#pragma unroll
    for (int p = 0; p < 8; p++) {
        int c = p * 16 + cl;
        int plane = b * 128 + c;
        size_t pixo = (size_t)h * Wd + seg * 64 + px4 * 4;
        const float4 a = *(const float4*)(rawAF + ((size_t)b * 256 + c) * HW + pixo);
        float4 f = *(const float4*)(rawAF + ((size_t)b * 256 + 128 + c) * HW + pixo);
        float m = mu[plane], rs = rsig[plane];
        float4 o;
        float v;
        v = (f.x - m) * rs; v = v > 0.f ? v : 0.2f * v; o.x = v * a.x;
        v = (f.y - m) * rs; v = v > 0.f ? v : 0.2f * v; o.y = v * a.y;
        v = (f.z - m) * rs; v = v > 0.f ? v : 0.2f * v; o.z = v * a.z;
        v = (f.w - m) * rs; v = v > 0.f ? v : 0.2f * v; o.w = v * a.w;
        *(float4*)(xa + (size_t)plane * HW + pixo) = o;
    }
}

// ---- deformable conv: prefetch-pipelined LDS-tile gather -> bf16 im2col -> MFMA ----
__global__ __launch_bounds__(256, 3) void deform_mfma_k(
    const float* __restrict__ xa, const float* __restrict__ om,
    const unsigned short* __restrict__ wpkO, const float* __restrict__ b_org,
    float* __restrict__ out, int ldc, int ch0) {
    const int seg = blockIdx.x, h = blockIdx.y, b = blockIdx.z;
    const int t = threadIdx.x;
    const int lane = t & 63, llo = t & 15, lhi = (t >> 4) & 3;
    const int wid = t >> 6;
    const int cb = seg * 64;

    __shared__ unsigned short sv[4][9][64][8];
    __shared__ unsigned xt[8 * 6 * 72];

    int prA[3][4];
    float prW[3][4];
    int prT0[3];
    int prOff[3];
    bool prV[3], prOK[3];

    const float* omb = om + (size_t)b * 32 * HW;
#pragma unroll
    for (int u = 0; u < 3; u++) {
        bool valid;
        int pc;
        if (u < 2) { valid = true; pc = t + u * 256; }
        else { valid = (t & 3) == 0; pc = 512 + (t >> 2); }
        int tap = pc >> 6, pxl = pc & 63;
        int ww = cb + pxl;
        int pix = h * Wd + ww;
        float dy = omb[(size_t)(2 * tap) * HW + pix];
        float dxv = omb[(size_t)(2 * tap + 1) * HW + pix];
        float msk = sigmoidf_(omb[(size_t)(18 + tap) * HW + pix]);
        float yy = dy + (float)(h + tap / 3 - 1);
        float xx = dxv + (float)(ww + tap % 3 - 1);
        float y0f = floorf(yy), x0f = floorf(xx);
        float wy = yy - y0f, wx = xx - x0f;
        int y0 = (int)y0f, x0 = (int)x0f;
#pragma unroll
        for (int c2 = 0; c2 < 4; c2++) {
            int ddy = c2 >> 1, ddx = c2 & 1;
            int yi = y0 + ddy, xi = x0 + ddx;
            bool vc = (yi >= 0) && (yi < Hh) && (xi >= 0) && (xi < Wd);
            int yc = min(max(yi, 0), Hh - 1), xc = min(max(xi, 0), Wd - 1);
            float wt = (ddy ? wy : 1.f - wy) * (ddx ? wx : 1.f - wx);
            prA[u][c2] = yc * Wd + xc;
            prW[u][c2] = vc ? wt * msk : 0.f;
        }
        int ty0 = y0 - (h - 2);
        int tx0 = x0 - (cb - 2);
        prOK[u] = ((unsigned)ty0 <= 4u) && ((unsigned)tx0 <= 70u);
        prT0[u] = ty0 * 72 + tx0;
        prOff[u] = tap * 64 + pxl;
        prV[u] = valid;
    }

    floatx4 acc[2][4];
#pragma unroll
    for (int c = 0; c < 2; c++)
#pragma unroll
        for (int ps = 0; ps < 4; ps++) acc[c][ps] = (floatx4){0.f, 0.f, 0.f, 0.f};

    const float* xab = xa + (size_t)b * Cc * HW;
    unsigned short* svf = &sv[0][0][0][0];

    float R[4][8];

    auto issue_stage = [&](int nc) {
        const int cbase = nc * 16;
#pragma unroll
        for (int it = 0; it < 4; it++) {
            int task = t + it * 256;
            if (task < 864) {
                int col = task % 72;
                int rg = task / 72;
                int row = rg % 6, grp = rg / 6;
                int r = h - 2 + row, cX = cb - 2 + col;
                int rc = min(max(r, 0), Hh - 1), cc = min(max(cX, 0), Wd - 1);
                const float* p = xab + (size_t)(cbase + grp * 8) * HW + rc * Wd + cc;
#pragma unroll
                for (int j = 0; j < 8; j++) R[it][j] = p[(size_t)j * HW];
            }
        }
    };

    issue_stage(0);

    for (int chunk = 0; chunk < 4; ++chunk) {
#pragma unroll
        for (int half = 0; half < 2; ++half) {
            barrier_lgkm();
#pragma unroll
            for (int it = 0; it < 4; it++) {
                int task = t + it * 256;
                if (task < 864) {
                    int col = task % 72;
                    int rg = task / 72;
                    int row = rg % 6, grp = rg / 6;
                    int r = h - 2 + row, cX = cb - 2 + col;
                    bool ok = ((unsigned)r < (unsigned)Hh) && ((unsigned)cX < (unsigned)Wd);
                    int cell = row * 72 + col;
#pragma unroll
                    for (int k = 0; k < 4; k++) {
                        float lo = ok ? R[it][2 * k] : 0.f;
                        float hi = ok ? R[it][2 * k + 1] : 0.f;
                        xt[(grp * 4 + k) * 432 + cell] = cvtpk(lo, hi);
                    }
                }
            }
            int nc = chunk * 2 + half + 1;
            if (nc < 8) issue_stage(nc);
            barrier_lgkm();
#pragma unroll
            for (int u = 0; u < 3; u++) {
                if (!prV[u]) continue;
                const float w0 = prW[u][0], w1 = prW[u][1], w2 = prW[u][2], w3 = prW[u][3];
                if (prOK[u]) {
                    const int d0 = prT0[u];
                    unsigned q[8];
#pragma unroll
                    for (int c2 = 0; c2 < 8; c2++) {
                        unsigned c00 = xt[c2 * 432 + d0];
                        unsigned c01 = xt[c2 * 432 + d0 + 1];
                        unsigned c10 = xt[c2 * 432 + d0 + 72];
                        unsigned c11 = xt[c2 * 432 + d0 + 73];
                        float va = w0 * bflo(c00) + w1 * bflo(c01) + w2 * bflo(c10) + w3 * bflo(c11);
                        float vb = w0 * bfhi(c00) + w1 * bfhi(c01) + w2 * bfhi(c10) + w3 * bfhi(c11);
                        q[c2] = cvtpk(va, vb);
                    }
                    *(uint4*)(svf + ((size_t)((half * 2 + 0) * 576 + prOff[u]) << 3)) =
                        make_uint4(q[0], q[1], q[2], q[3]);
                    *(uint4*)(svf + ((size_t)((half * 2 + 1) * 576 + prOff[u]) << 3)) =
                        make_uint4(q[4], q[5], q[6], q[7]);
                } else {
                    const int a0 = prA[u][0], a1 = prA[u][1], a2 = prA[u][2], a3 = prA[u][3];
                    const float* pb = xab + (size_t)(chunk * 32 + half * 16) * HW;
#pragma unroll
                    for (int cg2 = 0; cg2 < 2; cg2++) {
                        unsigned q[4];
#pragma unroll
                        for (int pair = 0; pair < 4; pair++) {
                            const float* p0 = pb + (size_t)(cg2 * 8 + 2 * pair) * HW;
                            const float* p1 = p0 + HW;
                            float va = w0 * p0[a0] + w1 * p0[a1] + w2 * p0[a2] + w3 * p0[a3];
                            float vb = w0 * p1[a0] + w1 * p1[a1] + w2 * p1[a2] + w3 * p1[a3];
                            q[pair] = cvtpk(va, vb);
                        }
                        *(uint4*)(svf + ((size_t)((half * 2 + cg2) * 576 + prOff[u]) << 3)) =
                            make_uint4(q[0], q[1], q[2], q[3]);
                    }
                }
            }
        }
        barrier_lgkm();
#pragma unroll
        for (int tap = 0; tap < 9; ++tap) {
            short8v af[2];
#pragma unroll
            for (int c = 0; c < 2; c++) {
                int cot = wid * 2 + c;
                af[c] = *(const short8v*)(wpkO + ((((size_t)cot * 4 + chunk) * 9 + tap) * 64 + lane) * 8);
            }
            short8v bf[4];
#pragma unroll
            for (int ps = 0; ps < 4; ps++)
                bf[ps] = *(const short8v*)&sv[lhi][tap][ps * 16 + llo][0];
#pragma unroll
            for (int c = 0; c < 2; c++)
#pragma unroll
                for (int ps = 0; ps < 4; ps++)
                    acc[c][ps] = MFMA16(af[c], bf[ps], acc[c][ps]);
        }
    }

#pragma unroll
    for (int c = 0; c < 2; c++)
#pragma unroll
        for (int ps = 0; ps < 4; ps++)
#pragma unroll
            for (int reg = 0; reg < 4; reg++) {
                int co = (wid * 2 + c) * 16 + lhi * 4 + reg;
                int px = cb + ps * 16 + llo;
                out[((size_t)b * ldc + ch0 + co) * HW + h * Wd + px] = acc[c][ps][reg] + b_org[co];
            }
}

// ---- out = xa + lrelu(norm(dconv)) * (1 - attn) ----
__global__ void final_k(const float* __restrict__ rawAF, const float* __restrict__ xa,
                        const float* __restrict__ mu, const float* __restrict__ rsig,
                        float* __restrict__ outp) {
    size_t i4 = (size_t)blockIdx.x * BDIM + threadIdx.x;
    const size_t n4 = (size_t)BB * Cc * HW / 4;
    if (i4 >= n4) return;
    int plane = (int)(i4 / (HW / 4));
    int w4 = (int)(i4 % (HW / 4));
    int b = plane >> 7, c = plane & 127;
    const float4 a = *(const float4*)(rawAF + ((size_t)b * 256 + c) * HW + w4 * 4);
    float4 d = *(const float4*)(rawAF + ((size_t)b * 256 + 128 + c) * HW + w4 * 4);
    float4 xv = *(const float4*)(xa + (size_t)plane * HW + w4 * 4);
    float m = mu[plane], rs = rsig[plane];
    float4 o;
    float v;
    v = (d.x - m) * rs; v = v > 0.f ? v : 0.2f * v; o.x = xv.x + v * (1.f - a.x);
    v = (d.y - m) * rs; v = v > 0.f ? v : 0.2f * v; o.y = xv.y + v * (1.f - a.y);
    v = (d.z - m) * rs; v = v > 0.f ? v : 0.2f * v; o.z = xv.z + v * (1.f - a.z);
    v = (d.w - m) * rs; v = v > 0.f ? v : 0.2f * v; o.w = xv.w + v * (1.f - a.w);
    *(float4*)(outp + (size_t)plane * HW + w4 * 4) = o;
}

extern "C" void kernel_launch(void* const* d_in, const int* in_sizes, int n_in,
                              void* d_out, int out_size, void* d_ws, size_t ws_size,
                              hipStream_t stream) {
    const float* x      = (const float*)d_in[0];
    const float* w_attn = (const float*)d_in[1];
    const float* b_attn = (const float*)d_in[2];
    const float* w_feat = (const float*)d_in[3];
    const float* b_feat = (const float*)d_in[4];
    const float* w_org  = (const float*)d_in[5];
    const float* b_org  = (const float*)d_in[6];
    const float* w_off  = (const float*)d_in[7];
    const float* b_off  = (const float*)d_in[8];
    const float* w_mask = (const float*)d_in[9];
    const float* b_mask = (const float*)d_in[10];
    float* out = (float*)d_out;
    (void)in_sizes; (void)n_in; (void)out_size; (void)ws_size;

    float* ws = (float*)d_ws;
    size_t o = 0;
    float* rawAF = ws + o; o += (size_t)BB * 256 * HW;  // ch0-127: attn(sig); ch128-255: featRaw -> dconv
    float* xa    = ws + o; o += (size_t)BB * Cc * HW;
    float* offm  = ws + o; o += (size_t)BB * 32 * HW;
    unsigned short* wpkAF = (unsigned short*)(ws + o); o += 16 * 18432 / 2;
    unsigned short* wpkO  = (unsigned short*)(ws + o); o += 8 * 18432 / 2;
    unsigned short* wpkOM = (unsigned short*)(ws + o); o += 2 * 18432 / 2;
    float* bOM = ws + o; o += 32;
    float* mu1 = ws + o; o += 512;
    float* rs1 = ws + o; o += 512;
    float* mu2 = ws + o; o += 512;
    float* rs2 = ws + o; o += 512;

    repack_conv_k<<<(8 * 18432 + BDIM - 1) / BDIM, BDIM, 0, stream>>>(w_attn, wpkAF, 8, 128);
    repack_conv_k<<<(8 * 18432 + BDIM - 1) / BDIM, BDIM, 0, stream>>>(w_feat, wpkAF + 8 * 18432, 8, 128);
    repack_conv_k<<<(8 * 18432 + BDIM - 1) / BDIM, BDIM, 0, stream>>>(w_org, wpkO, 8, 128);
    repack_om_k<<<(2 * 18432 + BDIM - 1) / BDIM, BDIM, 0, stream>>>(w_off, w_mask, wpkOM);
    pack_bom_k<<<1, 32, 0, stream>>>(b_off, b_mask, bOM);

    // fused attn+feat conv: 256 couts, ROWS=2, XCD-swizzled. 1024 blocks.
    conv2_k<4, 2, 2, true><<<1024, BDIM, 0, stream>>>(
        x, wpkAF, b_attn, b_feat, 128, 128, rawAF, 256, 0);

    inorm_stats_k<<<BB * Cc, BDIM, 0, stream>>>(rawAF, mu1, rs1, 256, 128);

    xattned_k<<<dim3(2, Hh, BB), BDIM, 0, stream>>>(rawAF, mu1, rs1, xa);

    // off/mask conv: 32 padded couts, ROWS=2. 256 blocks (1/CU).
    conv2_k<2, 1, 2, false><<<256, BDIM, 0, stream>>>(
        xa, wpkOM, bOM, bOM, 32, 0, offm, 32, 0);

    deform_mfma_k<<<dim3(2, Hh, BB), BDIM, 0, stream>>>(
        xa, offm, wpkO, b_org, rawAF, 256, 128);

    inorm_stats_k<<<BB * Cc, BDIM, 0, stream>>>(rawAF, mu2, rs2, 256, 128);

    const int n4 = BB * Cc * HW / 4;
    final_k<<<(n4 + BDIM - 1) / BDIM, BDIM, 0, stream>>>(rawAF, xa, mu2, rs2, out);
}

// Round 8
// 225.687 us; speedup vs baseline: 1.5944x; 1.0408x over previous
//
#include <hip/hip_runtime.h>
#include <math.h>

#define BDIM 256
constexpr int BB = 4, Cc = 128, Hh = 128, Wd = 128, HW = Hh * Wd;
constexpr float EPSv = 1e-5f;

typedef __attribute__((ext_vector_type(8))) short short8v;
typedef __attribute__((ext_vector_type(4))) float floatx4;

#define MFMA16(a, b, c) __builtin_amdgcn_mfma_f32_16x16x32_bf16((a), (b), (c), 0, 0, 0)

__device__ __forceinline__ float sigmoidf_(float v) { return 1.f / (1.f + __expf(-v)); }

__device__ __forceinline__ unsigned short f2bf(float f) {
    union { float f; unsigned u; } v; v.f = f;
    unsigned r = v.u + 0x7FFFu + ((v.u >> 16) & 1u);
    return (unsigned short)(r >> 16);
}
__device__ __forceinline__ unsigned cvtpk(float a, float b) {
    unsigned r;
    asm("v_cvt_pk_bf16_f32 %0, %1, %2" : "=v"(r) : "v"(a), "v"(b));
    return r;
}
__device__ __forceinline__ float bflo(unsigned u) { union { unsigned u; float f; } v; v.u = u << 16; return v.f; }
__device__ __forceinline__ float bfhi(unsigned u) { union { unsigned u; float f; } v; v.u = u & 0xFFFF0000u; return v.f; }
__device__ __forceinline__ float bfu(unsigned short u) { union { unsigned u; float f; } v; v.u = ((unsigned)u) << 16; return v.f; }

// LDS-only barrier: does NOT drain vmcnt (in-flight prefetch survives).
__device__ __forceinline__ void barrier_lgkm() {
    asm volatile("s_waitcnt lgkmcnt(0)" ::: "memory");
    __builtin_amdgcn_s_barrier();
}

// async global->LDS, 16B per lane; lds dest = uniform base + lane*16
__device__ __forceinline__ void gload16(const void* g, void* l) {
    __builtin_amdgcn_global_load_lds(
        (const __attribute__((address_space(1))) unsigned int*)g,
        (__attribute__((address_space(3))) unsigned int*)l, 16, 0, 0);
}

// ---- weight repack into per-lane MFMA fragment order ----
__global__ void repack_conv_k(const float* __restrict__ w, unsigned short* __restrict__ dst,
                              int ncot, int cout) {
    int idx = blockIdx.x * BDIM + threadIdx.x;
    int total = ncot * 4 * 9 * 64 * 8;
    if (idx >= total) return;
    int i = idx & 7;
    int lane = (idx >> 3) & 63;
    int tap = (idx >> 9) % 9;
    int chunk = (idx / (9 * 512)) & 3;
    int cot = idx / (4 * 9 * 512);
    int co = cot * 16 + (lane & 15);
    int ci = chunk * 32 + (lane >> 4) * 8 + i;
    float v = (co < cout) ? w[((size_t)co * Cc + ci) * 9 + tap] : 0.f;
    dst[idx] = f2bf(v);
}

__global__ void repack_om_k(const float* __restrict__ w_off, const float* __restrict__ w_mask,
                            unsigned short* __restrict__ dst) {
    int idx = blockIdx.x * BDIM + threadIdx.x;
    int total = 2 * 4 * 9 * 64 * 8;
    if (idx >= total) return;
    int i = idx & 7;
    int lane = (idx >> 3) & 63;
    int tap = (idx >> 9) % 9;
    int chunk = (idx / (9 * 512)) & 3;
    int cot = idx / (4 * 9 * 512);
    int co = cot * 16 + (lane & 15);
    int ci = chunk * 32 + (lane >> 4) * 8 + i;
    float v = 0.f;
    if (co < 18)      v = w_off[((size_t)co * Cc + ci) * 9 + tap];
    else if (co < 27) v = w_mask[((size_t)(co - 18) * Cc + ci) * 9 + tap];
    dst[idx] = f2bf(v);
}

__global__ void pack_bom_k(const float* __restrict__ b_off, const float* __restrict__ b_mask,
                           float* __restrict__ bom) {
    int i = threadIdx.x;
    if (i < 32) bom[i] = (i < 18) ? b_off[i] : (i < 27 ? b_mask[i - 18] : 0.f);
}

// ---- x (NCHW f32) -> dst (NHWC bf16, guarded base) ----
__global__ __launch_bounds__(256) void tobf_k(const float* __restrict__ x,
                                              unsigned short* __restrict__ dst) {
    const int h = blockIdx.x, b = blockIdx.y;
    const int t = threadIdx.x;
    __shared__ unsigned short lt[16][128];
    const int ciq = t >> 4, wg = t & 15;
    const int w = t >> 1, half = t & 1;
    for (int s = 0; s < 8; s++) {
        const float* p = x + ((size_t)(b * 128 + s * 16 + ciq) * HW + h * 128 + wg * 8);
        float4 a = *(const float4*)p;
        float4 c = *(const float4*)(p + 4);
        *(uint4*)&lt[ciq][wg * 8] =
            make_uint4(cvtpk(a.x, a.y), cvtpk(a.z, a.w), cvtpk(c.x, c.y), cvtpk(c.z, c.w));
        __syncthreads();
        unsigned r[4];
#pragma unroll
        for (int k = 0; k < 4; k++) {
            unsigned lo = lt[half * 8 + 2 * k][w];
            unsigned hi = lt[half * 8 + 2 * k + 1][w];
            r[k] = lo | (hi << 16);
        }
        *(uint4*)(dst + ((size_t)b * HW + h * 128 + w) * 128 + s * 16 + half * 8) =
            make_uint4(r[0], r[1], r[2], r[3]);
        __syncthreads();
    }
}

// ---- MFMA implicit-GEMM conv3x3 (pad=1), global_load_lds pipelined, ROWS=2 ----
// src: NHWC bf16 with +-1 guard row. LDS xs[buf][cigrp][row4][col128][8ci].
template <int COTPB, int WCO, bool SWZ>
__global__ __launch_bounds__(256, 2) void conv3_k(
    const unsigned short* __restrict__ src, const unsigned short* __restrict__ wpk,
    const float* __restrict__ biasA, const float* __restrict__ biasB,
    int bsplit, int sigsplit,
    float* __restrict__ out, int ldc, int ch0) {
    constexpr int ROWS = 2;
    constexpr int WPX = 4 / WCO;
    constexpr int PXW = 128 / WPX;
    constexpr int PS = PXW / 16;
    constexpr int HB = 128 / ROWS;

    const int t = threadIdx.x;
    const int lane = t & 63, llo = t & 15, lhi = (t >> 4) & 3;
    const int widu = __builtin_amdgcn_readfirstlane(t >> 6);
    const int wr = widu / WPX, wc = widu % WPX;

    int cbi, h0, b;
    if (SWZ) {
        int n = blockIdx.x;
        int xcd = n & 7, j = n >> 3;
        int g = (j >> 2) * 8 + xcd;
        cbi = j & 3;
        h0 = (g % HB) * ROWS;
        b = g / HB;
    } else {
        cbi = 0;
        h0 = ((int)blockIdx.x % HB) * ROWS;
        b = (int)blockIdx.x / HB;
    }
    const int cotbase = cbi * COTPB + wr * 2;

    __shared__ unsigned short xs[2][4][4][128][8];  // 64 KB

    floatx4 acc[2][ROWS][PS];
#pragma unroll
    for (int c = 0; c < 2; c++)
#pragma unroll
        for (int row = 0; row < ROWS; row++)
#pragma unroll
            for (int ps = 0; ps < PS; ps++) acc[c][row][ps] = (floatx4){0.f, 0.f, 0.f, 0.f};

    const unsigned short* srcb = src + ((size_t)b * HW + (size_t)(h0 - 1) * 128) * 128;

    auto stage = [&](int chunk, int buf) {
        const unsigned short* sb = srcb + chunk * 32 + widu * 8;
        unsigned short* db = &xs[buf][widu][0][0][0];
#pragma unroll
        for (int i = 0; i < 8; i++) {
            const unsigned short* g = sb + (size_t)(i * 64 + lane) * 128;
            gload16(g, db + i * 512);
        }
    };

    short8v afr[9][2];

    stage(0, 0);
    __syncthreads();

    for (int chunk = 0; chunk < 4; ++chunk) {
        const int buf = chunk & 1;
        if (chunk < 3) stage(chunk + 1, buf ^ 1);
#pragma unroll
        for (int tap = 0; tap < 9; tap++)
#pragma unroll
            for (int c = 0; c < 2; c++)
                afr[tap][c] = *(const short8v*)(wpk +
                    ((((size_t)(cotbase + c) * 4 + chunk) * 9 + tap) * 64 + lane) * 8);
        const int wcb = wc * PXW;
#pragma unroll
        for (int tap = 0; tap < 9; ++tap) {
            const int r = tap / 3, dx = tap % 3;
#pragma unroll
            for (int row = 0; row < ROWS; row++) {
                const int rowr = row + r;
                const int hh = h0 - 1 + rowr;
                if ((unsigned)hh < 128u) {
#pragma unroll
                    for (int ps = 0; ps < PS; ps++) {
                        int colr = wcb + ps * 16 + llo + dx - 1;
                        int colc = min(max(colr, 0), 127);
                        short8v bfv = *(const short8v*)&xs[buf][lhi][rowr][colc][0];
                        if (colr != colc) bfv = (short8v)(short)0;
#pragma unroll
                        for (int c = 0; c < 2; c++)
                            acc[c][row][ps] = MFMA16(afr[tap][c], bfv, acc[c][row][ps]);
                    }
                }
            }
        }
        __syncthreads();
    }

    const int cbase = cbi * (COTPB * 16);
    const float* bp = (cbase < bsplit) ? biasA : biasB;
    const int bshift = (cbase < bsplit) ? 0 : bsplit;
    const bool dosig = cbase < sigsplit;
#pragma unroll
    for (int c = 0; c < 2; c++)
#pragma unroll
        for (int row = 0; row < ROWS; row++)
#pragma unroll
            for (int ps = 0; ps < PS; ps++)
#pragma unroll
                for (int reg = 0; reg < 4; reg++) {
                    int co = cbase + (wr * 2 + c) * 16 + lhi * 4 + reg;
                    int px = wc * PXW + ps * 16 + llo;
                    float v = acc[c][row][ps][reg] + bp[co - bshift];
                    if (dosig) v = sigmoidf_(v);
                    out[((size_t)b * ldc + ch0 + co) * HW + (h0 + row) * Wd + px] = v;
                }
}

// ---- instance-norm stats ----
__global__ __launch_bounds__(256) void inorm_stats_k(const float* __restrict__ src,
                                                     float* __restrict__ mu, float* __restrict__ rsig,
                                                     int chTot, int ch0) {
    const int bc = blockIdx.x;
    const int b = bc >> 7, c = bc & 127;
    const float4* p = (const float4*)(src + ((size_t)b * chTot + ch0 + c) * HW);
    float s = 0.f, s2 = 0.f;
    for (int i = threadIdx.x; i < HW / 4; i += BDIM) {
        float4 v = p[i];
        s += v.x + v.y + v.z + v.w;
        s2 += v.x * v.x + v.y * v.y + v.z * v.z + v.w * v.w;
    }
    __shared__ float ss[BDIM], sq[BDIM];
    int t = threadIdx.x;
    ss[t] = s; sq[t] = s2;
    __syncthreads();
    for (int off = BDIM / 2; off > 0; off >>= 1) {
        if (t < off) { ss[t] += ss[t + off]; sq[t] += sq[t + off]; }
        __syncthreads();
    }
    if (t == 0) {
        float m = ss[0] / HW;
        float var = sq[0] / HW - m * m;
        mu[bc] = m;
        rsig[bc] = rsqrtf(var + EPSv);
    }
}

// ---- xa = lrelu(norm(featRaw)) * attn -> xabf (NHWC bf16, guarded base) ----
__global__ __launch_bounds__(256) void xattned2_k(const float* __restrict__ rawAF,
                                                  const float* __restrict__ mu,
                                                  const float* __restrict__ rsig,
                                                  unsigned short* __restrict__ xabfG) {
    const int seg = blockIdx.x, h = blockIdx.y, b = blockIdx.z;
    const int t = threadIdx.x;
    __shared__ unsigned short la[64][128];
    const int px4 = t & 15, cl = t >> 4;
#pragma unroll
    for (int p = 0; p < 8; p++) {
        int c = p * 16 + cl;
        int plane = b * 128 + c;
        size_t pixo = (size_t)h * Wd + seg * 64 + px4 * 4;
        float4 a = *(const float4*)(rawAF + ((size_t)b * 256 + c) * HW + pixo);
        float4 f = *(const float4*)(rawAF + ((size_t)b * 256 + 128 + c) * HW + pixo);
        float m = mu[plane], rs = rsig[plane];
        float vs[4];
        float v;
        v = (f.x - m) * rs; v = v > 0.f ? v : 0.2f * v; vs[0] = v * a.x;
        v = (f.y - m) * rs; v = v > 0.f ? v : 0.2f * v; vs[1] = v * a.y;
        v = (f.z - m) * rs; v = v > 0.f ? v : 0.2f * v; vs[2] = v * a.z;
        v = (f.w - m) * rs; v = v > 0.f ? v : 0.2f * v; vs[3] = v * a.w;
#pragma unroll
        for (int j = 0; j < 4; j++) la[px4 * 4 + j][c] = f2bf(vs[j]);
    }
    __syncthreads();
    const int px = t >> 2, part = t & 3;
    const uint4* lp = (const uint4*)&la[px][part * 32];
    unsigned short* dp = xabfG + ((size_t)b * HW + h * 128 + seg * 64 + px) * 128 + part * 32;
    uint4 v0 = lp[0], v1 = lp[1], v2 = lp[2], v3 = lp[3];
    *(uint4*)dp = v0;
    *(uint4*)(dp + 8) = v1;
    *(uint4*)(dp + 16) = v2;
    *(uint4*)(dp + 24) = v3;
}

// ---- deformable conv: LDS-tile gather (bf16 NHWC source) -> im2col -> MFMA ----
__global__ __launch_bounds__(256, 3) void deform_mfma_k(
    const unsigned short* __restrict__ xabfG, const float* __restrict__ om,
    const unsigned short* __restrict__ wpkO, const float* __restrict__ b_org,
    float* __restrict__ out, int ldc, int ch0) {
    const int seg = blockIdx.x, h = blockIdx.y, b = blockIdx.z;
    const int t = threadIdx.x;
    const int lane = t & 63, llo = t & 15, lhi = (t >> 4) & 3;
    const int wid = t >> 6;
    const int cb = seg * 64;

    __shared__ unsigned short sv[4][9][64][8];
    __shared__ unsigned xt[8 * 6 * 72];

    int prA[3][4];
    float prW[3][4];
    int prT0[3];
    int prOff[3];
    bool prV[3], prOK[3];

    const float* omb = om + (size_t)b * 32 * HW;
#pragma unroll
    for (int u = 0; u < 3; u++) {
        bool valid;
        int pc;
        if (u < 2) { valid = true; pc = t + u * 256; }
        else { valid = (t & 3) == 0; pc = 512 + (t >> 2); }
        int tap = pc >> 6, pxl = pc & 63;
        int ww = cb + pxl;
        int pix = h * Wd + ww;
        float dy = omb[(size_t)(2 * tap) * HW + pix];
        float dxv = omb[(size_t)(2 * tap + 1) * HW + pix];
        float msk = sigmoidf_(omb[(size_t)(18 + tap) * HW + pix]);
        float yy = dy + (float)(h + tap / 3 - 1);
        float xx = dxv + (float)(ww + tap % 3 - 1);
        float y0f = floorf(yy), x0f = floorf(xx);
        float wy = yy - y0f, wx = xx - x0f;
        int y0 = (int)y0f, x0 = (int)x0f;
#pragma unroll
        for (int c2 = 0; c2 < 4; c2++) {
            int ddy = c2 >> 1, ddx = c2 & 1;
            int yi = y0 + ddy, xi = x0 + ddx;
            bool vc = (yi >= 0) && (yi < Hh) && (xi >= 0) && (xi < Wd);
            int yc = min(max(yi, 0), Hh - 1), xc = min(max(xi, 0), Wd - 1);
            float wt = (ddy ? wy : 1.f - wy) * (ddx ? wx : 1.f - wx);
            prA[u][c2] = yc * Wd + xc;
            prW[u][c2] = vc ? wt * msk : 0.f;
        }
        int ty0 = y0 - (h - 2);
        int tx0 = x0 - (cb - 2);
        prOK[u] = ((unsigned)ty0 <= 4u) && ((unsigned)tx0 <= 70u);
        prT0[u] = ty0 * 72 + tx0;
        prOff[u] = tap * 64 + pxl;
        prV[u] = valid;
    }

    floatx4 acc[2][4];
#pragma unroll
    for (int c = 0; c < 2; c++)
#pragma unroll
        for (int ps = 0; ps < 4; ps++) acc[c][ps] = (floatx4){0.f, 0.f, 0.f, 0.f};

    const unsigned short* xab = xabfG + (size_t)b * HW * 128;
    unsigned short* svf = &sv[0][0][0][0];

    uint4 U[4];

    auto issue_stage = [&](int nc) {
        const int cbase = nc * 16;
#pragma unroll
        for (int it = 0; it < 4; it++) {
            int task = t + it * 256;
            if (task < 864) {
                int col = task % 72;
                int rg = task / 72;
                int row = rg % 6, grp = rg / 6;
                int r = h - 2 + row, cX = cb - 2 + col;
                int rc = min(max(r, 0), Hh - 1), cc = min(max(cX, 0), Wd - 1);
                U[it] = *(const uint4*)(xab + ((size_t)rc * 128 + cc) * 128 + cbase + grp * 8);
            }
        }
    };

    issue_stage(0);

    for (int chunk = 0; chunk < 4; ++chunk) {
#pragma unroll
        for (int half = 0; half < 2; ++half) {
            barrier_lgkm();
#pragma unroll
            for (int it = 0; it < 4; it++) {
                int task = t + it * 256;
                if (task < 864) {
                    int col = task % 72;
                    int rg = task / 72;
                    int row = rg % 6, grp = rg / 6;
                    int cell = row * 72 + col;
                    unsigned q0 = U[it].x, q1 = U[it].y, q2 = U[it].z, q3 = U[it].w;
                    xt[(grp * 4 + 0) * 432 + cell] = q0;
                    xt[(grp * 4 + 1) * 432 + cell] = q1;
                    xt[(grp * 4 + 2) * 432 + cell] = q2;
                    xt[(grp * 4 + 3) * 432 + cell] = q3;
                }
            }
            int nc = chunk * 2 + half + 1;
            if (nc < 8) issue_stage(nc);
            barrier_lgkm();
#pragma unroll
            for (int u = 0; u < 3; u++) {
                if (!prV[u]) continue;
                const float w0 = prW[u][0], w1 = prW[u][1], w2 = prW[u][2], w3 = prW[u][3];
                if (prOK[u]) {
                    const int d0 = prT0[u];
                    unsigned q[8];
#pragma unroll
                    for (int c2 = 0; c2 < 8; c2++) {
                        unsigned c00 = xt[c2 * 432 + d0];
                        unsigned c01 = xt[c2 * 432 + d0 + 1];
                        unsigned c10 = xt[c2 * 432 + d0 + 72];
                        unsigned c11 = xt[c2 * 432 + d0 + 73];
                        float va = w0 * bflo(c00) + w1 * bflo(c01) + w2 * bflo(c10) + w3 * bflo(c11);
                        float vb = w0 * bfhi(c00) + w1 * bfhi(c01) + w2 * bfhi(c10) + w3 * bfhi(c11);
                        q[c2] = cvtpk(va, vb);
                    }
                    *(uint4*)(svf + ((size_t)((half * 2 + 0) * 576 + prOff[u]) << 3)) =
                        make_uint4(q[0], q[1], q[2], q[3]);
                    *(uint4*)(svf + ((size_t)((half * 2 + 1) * 576 + prOff[u]) << 3)) =
                        make_uint4(q[4], q[5], q[6], q[7]);
                } else {
                    const int a0 = prA[u][0], a1 = prA[u][1], a2 = prA[u][2], a3 = prA[u][3];
                    const int cch = chunk * 32 + half * 16;
#pragma unroll
                    for (int cg2 = 0; cg2 < 2; cg2++) {
                        unsigned q[4];
#pragma unroll
                        for (int pair = 0; pair < 4; pair++) {
                            int co8 = cch + cg2 * 8 + 2 * pair;
                            unsigned c0 = *(const unsigned*)(xab + (size_t)a0 * 128 + co8);
                            unsigned c1 = *(const unsigned*)(xab + (size_t)a1 * 128 + co8);
                            unsigned c2v = *(const unsigned*)(xab + (size_t)a2 * 128 + co8);
                            unsigned c3 = *(const unsigned*)(xab + (size_t)a3 * 128 + co8);
                            float va = w0 * bflo(c0) + w1 * bflo(c1) + w2 * bflo(c2v) + w3 * bflo(c3);
                            float vb = w0 * bfhi(c0) + w1 * bfhi(c1) + w2 * bfhi(c2v) + w3 * bfhi(c3);
                            q[pair] = cvtpk(va, vb);
                        }
                        *(uint4*)(svf + ((size_t)((half * 2 + cg2) * 576 + prOff[u]) << 3)) =
                            make_uint4(q[0], q[1], q[2], q[3]);
                    }
                }
            }
        }
        barrier_lgkm();
#pragma unroll
        for (int tap = 0; tap < 9; ++tap) {
            short8v af[2];
#pragma unroll
            for (int c = 0; c < 2; c++) {
                int cot = wid * 2 + c;
                af[c] = *(const short8v*)(wpkO + ((((size_t)cot * 4 + chunk) * 9 + tap) * 64 + lane) * 8);
            }
            short8v bf[4];
#pragma unroll
            for (int ps = 0; ps < 4; ps++)
                bf[ps] = *(const short8v*)&sv[lhi][tap][ps * 16 + llo][0];
#pragma unroll
            for (int c = 0; c < 2; c++)
#pragma unroll
                for (int ps = 0; ps < 4; ps++)
                    acc[c][ps] = MFMA16(af[c], bf[ps], acc[c][ps]);
        }
    }

#pragma unroll
    for (int c = 0; c < 2; c++)
#pragma unroll
        for (int ps = 0; ps < 4; ps++)
#pragma unroll
            for (int reg = 0; reg < 4; reg++) {
                int co = (wid * 2 + c) * 16 + lhi * 4 + reg;
                int px = cb + ps * 16 + llo;
                out[((size_t)b * ldc + ch0 + co) * HW + h * Wd + px] = acc[c][ps][reg] + b_org[co];
            }
}

// ---- out = xa + lrelu(norm(dconv)) * (1 - attn) ; xa from xabf via LDS ----
__global__ __launch_bounds__(256) void final2_k(const float* __restrict__ rawAF,
                                                const unsigned short* __restrict__ xabfG,
                                                const float* __restrict__ mu,
                                                const float* __restrict__ rsig,
                                                float* __restrict__ outp) {
    const int seg = blockIdx.x, h = blockIdx.y, b = blockIdx.z;
    const int t = threadIdx.x;
    __shared__ unsigned short la[64][128];
    {
        const int px = t >> 2, part = t & 3;
        const unsigned short* sp = xabfG + ((size_t)b * HW + h * 128 + seg * 64 + px) * 128 + part * 32;
        uint4* lp = (uint4*)&la[px][part * 32];
        lp[0] = *(const uint4*)sp;
        lp[1] = *(const uint4*)(sp + 8);
        lp[2] = *(const uint4*)(sp + 16);
        lp[3] = *(const uint4*)(sp + 24);
    }
    __syncthreads();
    const int px4 = t & 15, cl = t >> 4;
#pragma unroll
    for (int p = 0; p < 8; p++) {
        int c = p * 16 + cl;
        int plane = b * 128 + c;
        size_t pixo = (size_t)h * Wd + seg * 64 + px4 * 4;
        float4 a = *(const float4*)(rawAF + ((size_t)b * 256 + c) * HW + pixo);
        float4 d = *(const float4*)(rawAF + ((size_t)b * 256 + 128 + c) * HW + pixo);
        float m = mu[plane], rs = rsig[plane];
        float4 o;
        float v;
        v = (d.x - m) * rs; v = v > 0.f ? v : 0.2f * v; o.x = bfu(la[px4 * 4 + 0][c]) + v * (1.f - a.x);
        v = (d.y - m) * rs; v = v > 0.f ? v : 0.2f * v; o.y = bfu(la[px4 * 4 + 1][c]) + v * (1.f - a.y);
        v = (d.z - m) * rs; v = v > 0.f ? v : 0.2f * v; o.z = bfu(la[px4 * 4 + 2][c]) + v * (1.f - a.z);
        v = (d.w - m) * rs; v = v > 0.f ? v : 0.2f * v; o.w = bfu(la[px4 * 4 + 3][c]) + v * (1.f - a.w);
        *(float4*)(outp + (size_t)plane * HW + pixo) = o;
    }
}

extern "C" void kernel_launch(void* const* d_in, const int* in_sizes, int n_in,
                              void* d_out, int out_size, void* d_ws, size_t ws_size,
                              hipStream_t stream) {
    const float* x      = (const float*)d_in[0];
    const float* w_attn = (const float*)d_in[1];
    const float* b_attn = (const float*)d_in[2];
    const float* w_feat = (const float*)d_in[3];
    const float* b_feat = (const float*)d_in[4];
    const float* w_org  = (const float*)d_in[5];
    const float* b_org  = (const float*)d_in[6];
    const float* w_off  = (const float*)d_in[7];
    const float* b_off  = (const float*)d_in[8];
    const float* w_mask = (const float*)d_in[9];
    const float* b_mask = (const float*)d_in[10];
    float* out = (float*)d_out;
    (void)in_sizes; (void)n_in; (void)out_size; (void)ws_size;

    // workspace layout (~93 MB):
    // rawAF (f32, BB x 256 x HW)          : attn | featRaw->dconv
    // regionA (ushort): [guard 16384] xbf/xabf (BB*HW*128) [guard 16384] , then offm f32
    float* ws = (float*)d_ws;
    float* rawAF = ws;
    unsigned short* regionA = (unsigned short*)(ws + (size_t)BB * 256 * HW);
    unsigned short* xbfG  = regionA + 16384;             // aliased: x-bf16 then xa-bf16
    const size_t bfElems = (size_t)BB * HW * 128;
    float* offm = (float*)(regionA + 2 * 16384 + bfElems);
    float* tail = offm + (size_t)BB * 32 * HW;
    unsigned short* wpkAF = (unsigned short*)tail;
    unsigned short* wpkO  = wpkAF + (size_t)16 * 18432;
    unsigned short* wpkOM = wpkO + (size_t)8 * 18432;
    float* bOM = (float*)(wpkOM + (size_t)2 * 18432);
    float* mu1 = bOM + 32;
    float* rs1 = mu1 + 512;
    float* mu2 = rs1 + 512;
    float* rs2 = mu2 + 512;

    repack_conv_k<<<(8 * 18432 + BDIM - 1) / BDIM, BDIM, 0, stream>>>(w_attn, wpkAF, 8, 128);
    repack_conv_k<<<(8 * 18432 + BDIM - 1) / BDIM, BDIM, 0, stream>>>(w_feat, wpkAF + 8 * 18432, 8, 128);
    repack_conv_k<<<(8 * 18432 + BDIM - 1) / BDIM, BDIM, 0, stream>>>(w_org, wpkO, 8, 128);
    repack_om_k<<<(2 * 18432 + BDIM - 1) / BDIM, BDIM, 0, stream>>>(w_off, w_mask, wpkOM);
    pack_bom_k<<<1, 32, 0, stream>>>(b_off, b_mask, bOM);

    // x -> bf16 NHWC
    tobf_k<<<dim3(Hh, BB), BDIM, 0, stream>>>(x, xbfG);

    // fused attn+feat conv: 256 couts, XCD-swizzled, 1024 blocks
    conv3_k<4, 2, true><<<1024, BDIM, 0, stream>>>(
        xbfG, wpkAF, b_attn, b_feat, 128, 128, rawAF, 256, 0);

    inorm_stats_k<<<BB * Cc, BDIM, 0, stream>>>(rawAF, mu1, rs1, 256, 128);

    // xa -> bf16 NHWC (aliases xbf region; xbf is dead now)
    xattned2_k<<<dim3(2, Hh, BB), BDIM, 0, stream>>>(rawAF, mu1, rs1, xbfG);

    // off/mask conv: 32 padded couts, 256 blocks
    conv3_k<2, 1, false><<<256, BDIM, 0, stream>>>(
        xbfG, wpkOM, bOM, bOM, 32, 0, offm, 32, 0);

    deform_mfma_k<<<dim3(2, Hh, BB), BDIM, 0, stream>>>(
        xbfG, offm, wpkO, b_org, rawAF, 256, 128);

    inorm_stats_k<<<BB * Cc, BDIM, 0, stream>>>(rawAF, mu2, rs2, 256, 128);

    final2_k<<<dim3(2, Hh, BB), BDIM, 0, stream>>>(rawAF, xbfG, mu2, rs2, out);
}